// Round 9
// baseline (167.555 us; speedup 1.0000x reference)
//
#include <hip/hip_runtime.h>
#include <hip/hip_bf16.h>
#include <cstdint>
#include <cstddef>

#define LOG2E 1.4426950408889634f

typedef __attribute__((ext_vector_type(8))) short short8;
typedef __attribute__((ext_vector_type(4))) float f32x4;

__device__ __forceinline__ float exp2f_fast(float x) { return __builtin_amdgcn_exp2f(x); }
__device__ __forceinline__ float rcp_fast(float x)   { return __builtin_amdgcn_rcpf(x); }
__device__ __forceinline__ float tanh_fast(float x) {
  float e = exp2f_fast(x * (2.0f * LOG2E));
  return 1.0f - 2.0f * rcp_fast(e + 1.0f);
}
__device__ __forceinline__ unsigned short f2b(float f) {  // f32 -> bf16 RNE
  union { float f; unsigned int u; } v; v.f = f;
  return (unsigned short)((v.u + 0x7FFFu + ((v.u >> 16) & 1u)) >> 16);
}
__device__ __forceinline__ float b2f(short h) {
  union { unsigned u; float f; } w; w.u = ((unsigned)(unsigned short)h) << 16;
  return w.f;
}

#define GLOAD_LDS16(g, l) \
  __builtin_amdgcn_global_load_lds((const __attribute__((address_space(1))) unsigned int*)(g), \
                                   (__attribute__((address_space(3))) unsigned int*)(l), 16, 0, 0)

// ---------------------------------------------------------------------------
// Skinny MFMA GEMM helper (M=32): out[b, n0..n0+127] += X @ W^T  (unchanged)
// ---------------------------------------------------------------------------
__device__ __forceinline__ void skinny_gemm(
    const float* __restrict__ W, int Kfull,
    const float* __restrict__ x0, const float* __restrict__ x1,
    const float* __restrict__ x2,
    int kbeg, int kend, int n0, float* __restrict__ out)
{
  __shared__ unsigned char sX[4096];   // 32 rows x 64 k bf16, XOR-swizzled
  const int tid = threadIdx.x, lane = tid & 63, wv = tid >> 6;
  const int l15 = lane & 15, l4 = lane >> 4;
  f32x4 acc[2][2];
#pragma unroll
  for (int m = 0; m < 2; ++m)
#pragma unroll
    for (int j = 0; j < 2; ++j) acc[m][j] = (f32x4){0.f, 0.f, 0.f, 0.f};

  const int srow = tid >> 3, skc = (tid & 7) * 8;
  const int sbyte = srow * 128 + ((skc * 2) ^ ((srow & 7) << 4));

  for (int k0 = kbeg; k0 < kend; k0 += 64) {
    const float* xs = (k0 < 1024) ? x0 : (k0 < 2048) ? x1 : x2;
    const float* xp = xs + srow * 1024 + (k0 & 1023) + skc;
    float4 a = *reinterpret_cast<const float4*>(xp);
    float4 b = *reinterpret_cast<const float4*>(xp + 4);
    short8 h;
    h[0] = (short)f2b(a.x); h[1] = (short)f2b(a.y); h[2] = (short)f2b(a.z); h[3] = (short)f2b(a.w);
    h[4] = (short)f2b(b.x); h[5] = (short)f2b(b.y); h[6] = (short)f2b(b.z); h[7] = (short)f2b(b.w);
    *reinterpret_cast<short8*>(sX + sbyte) = h;
    __syncthreads();
#pragma unroll
    for (int ks = 0; ks < 2; ++ks) {
      short8 af[2], bfr[2];
#pragma unroll
      for (int m = 0; m < 2; ++m) {
        int r = m * 16 + l15;
        af[m] = *reinterpret_cast<const short8*>(
            sX + r * 128 + (((ks * 64) + l4 * 16) ^ ((r & 7) << 4)));
      }
#pragma unroll
      for (int j = 0; j < 2; ++j) {
        int n = n0 + wv * 32 + j * 16 + l15;
        const float* wp = W + (size_t)n * Kfull + k0 + ks * 32 + l4 * 8;
        float4 wa = *reinterpret_cast<const float4*>(wp);
        float4 wb = *reinterpret_cast<const float4*>(wp + 4);
        short8 hb;
        hb[0] = (short)f2b(wa.x); hb[1] = (short)f2b(wa.y); hb[2] = (short)f2b(wa.z); hb[3] = (short)f2b(wa.w);
        hb[4] = (short)f2b(wb.x); hb[5] = (short)f2b(wb.y); hb[6] = (short)f2b(wb.z); hb[7] = (short)f2b(wb.w);
        bfr[j] = hb;
      }
#pragma unroll
      for (int m = 0; m < 2; ++m)
#pragma unroll
        for (int j = 0; j < 2; ++j)
          acc[m][j] = __builtin_amdgcn_mfma_f32_16x16x32_bf16(af[m], bfr[j], acc[m][j], 0, 0, 0);
    }
    __syncthreads();
  }
#pragma unroll
  for (int m = 0; m < 2; ++m)
#pragma unroll
    for (int j = 0; j < 2; ++j)
#pragma unroll
      for (int r = 0; r < 4; ++r)
        atomicAdd(out + (size_t)(m * 16 + l4 * 4 + r) * 1024 + (n0 + wv * 32 + j * 16 + l15),
                  acc[m][j][r]);
}

// ---------------------------------------------------------------------------
// convert_att2 v5: Wf->bf16 + att2pre + ALL ctx-independent gate GEMMs.
//   [0,128)    Wf convert
//   [128,144)  att2pre skinny gemm (Wd @ dh)
//   [144,208)  early gate: es 0-3 Wg k<2048 -> ztp; es 4-7 Wt -> tcp
// ---------------------------------------------------------------------------
__global__ __launch_bounds__(256) void convert_att2(
    const float* __restrict__ wf, unsigned short* __restrict__ wfb,
    const float* __restrict__ Wd, const float* __restrict__ dh,
    float* __restrict__ att2, const float* __restrict__ Wg,
    const float* __restrict__ Wt, const float* __restrict__ word,
    float* __restrict__ ztp, float* __restrict__ tcp)
{
  const int bid = blockIdx.x;
  if (bid < 128) {
    const int base = bid * 1024;
#pragma unroll
    for (int j = 0; j < 4; ++j) {
      int g = base + j * 256 + (int)threadIdx.x;
      const float* s = wf + (size_t)g * 8;
      float4 a = *reinterpret_cast<const float4*>(s);
      float4 b = *reinterpret_cast<const float4*>(s + 4);
      short8 o;
      o[0] = (short)f2b(a.x); o[1] = (short)f2b(a.y); o[2] = (short)f2b(a.z); o[3] = (short)f2b(a.w);
      o[4] = (short)f2b(b.x); o[5] = (short)f2b(b.y); o[6] = (short)f2b(b.z); o[7] = (short)f2b(b.w);
      *reinterpret_cast<short8*>(wfb + (size_t)g * 8) = o;
    }
  } else if (bid < 144) {
    int bid2 = bid - 128;
    int nt = bid2 & 7, ks = bid2 >> 3;
    skinny_gemm(Wd, 1024, dh, dh, dh, ks * 512, ks * 512 + 512, nt * 128, att2);
  } else {
    int eb = bid - 144;
    int es = eb >> 3, nt = eb & 7;
    if (es < 4)
      skinny_gemm(Wg, 3072, word, dh, dh, es * 512, es * 512 + 512, nt * 128, ztp);
    else
      skinny_gemm(Wt, 2048, word, dh, dh, (es - 4) * 512, (es - 4) * 512 + 512, nt * 128, tcp);
  }
}

// ---------------------------------------------------------------------------
// gate_gemm v5 (post-ctx only): Wg k in [2048,3072) and Ws. 8 x 4 blocks.
// ---------------------------------------------------------------------------
__global__ __launch_bounds__(256) void gate_gemm(
    const float* __restrict__ Wg, const float* __restrict__ Ws_,
    const float* __restrict__ word, const float* __restrict__ dh,
    const float* __restrict__ ctx,
    float* __restrict__ ztp, float* __restrict__ scp)
{
  const int nt = blockIdx.x, slot = blockIdx.y;
  if (slot < 2)
    skinny_gemm(Wg, 3072, word, dh, ctx, 2048 + slot * 512, 2048 + slot * 512 + 512, nt * 128, ztp);
  else
    skinny_gemm(Ws_, 1024, ctx, ctx, ctx, (slot - 2) * 512, (slot - 2) * 512 + 512, nt * 128, scp);
}

// ---------------------------------------------------------------------------
// att_gemm3 v6: m201-style FINE-GRAINED 4-PHASE tile body (8 barriers/tile,
// counted lgkm, vmcnt never drained to 0 mid-loop except the flight pack),
// keeping the R5 cross-barrier flight staging for f32 A.
// Per tile t (slot s=t&1; next slot s^1 safe to write: tile t-1 read it and
// finished all its reads before its final barrier):
//   P0: issue A0(8)+B0(4) reads      | BAR | lgkm(0)           | MFMA(0,0) | BAR
//   P1: issue B1(4); vmcnt(0)+pack A(t+1)(4 ds_wr); STAGE_B(t+1)
//                                    | BAR | lgkm(4) [reads<=wr]| MFMA(0,1) | BAR
//   P2: issue A1(8); flight1(A(t+2)) | BAR | lgkm(0)           | MFMA(1,0) | BAR
//   P3: flight2; vmcnt(8) [drains B-DMA only, 8 flights stay]   | BAR? ->
//                                    | BAR |                    | MFMA(1,1) | BAR
// vmcnt audit: at P1, outstanding = 8 flights (B-DMA(t) drained at t-1 P3)
// -> vmcnt(0) has 2-3 phases of cover. At P3, queue = [4 B-DMA][8 flights]
// -> vmcnt(8) drains only the (older) B-DMA, ~2 phases of cover.
// ---------------------------------------------------------------------------
__global__ __launch_bounds__(512, 2) void att_gemm3(
    const float* __restrict__ cap, const unsigned short* __restrict__ wfb,
    const float* __restrict__ att2pre, const float* __restrict__ bfv,
    const float* __restrict__ bdv, const float* __restrict__ Wa,
    float* __restrict__ scores)
{
  __shared__ __align__(16) unsigned char lds[131072];   // 2 slots x (A 32K + B 32K)
  const int tid = threadIdx.x, lane = tid & 63, wv = tid >> 6;
  // bijective XCD chunking: nwg=512, 8 XCDs, 64 jobs/XCD
  const int j = ((int)blockIdx.x & 7) * 64 + ((int)blockIdx.x >> 3);
  const int mt = j >> 2, nt = j & 3;            // 128 m-tiles x 4 n-tiles
  const int m0 = mt << 8, n0 = nt << 8;
  const int bb = m0 >> 10;                      // batch (256 | 1024)
  const int wm = wv >> 2, wn = wv & 3;          // 2M x 4N
  const int l15 = lane & 15, l4 = lane >> 4;
  const int r8 = lane >> 3, c8 = lane & 7;
  const unsigned swb = (unsigned)((l15 & 7) << 4);

  // A staging source: f32, inverse-swizzled column (bf16 byte off / 2).
  const float* capA = cap + (size_t)(m0 + wv * 32 + r8) * 1024 +
                      ((unsigned)((c8 * 16) ^ (r8 << 4)) >> 1);
  // B stage source (bf16 wfb, DMA path)
  const unsigned char* bSrc = (const unsigned char*)wfb +
      (size_t)(n0 + wv * 32 + r8) * 2048 + ((c8 * 16) ^ (r8 << 4));
  const unsigned ldsBase = (unsigned)(size_t)(&lds[0]);

  f32x4 acc[8][4];
#pragma unroll
  for (int mf = 0; mf < 8; ++mf)
#pragma unroll
    for (int nf = 0; nf < 4; ++nf) acc[mf][nf] = (f32x4){0.f, 0.f, 0.f, 0.f};

#define STAGE_B(t) do { \
    const int sl__ = (t) & 1; \
    unsigned char* db__ = lds + sl__ * 65536 + 32768 + wv * 4096; \
    const unsigned char* gb__ = bSrc + (t) * 128; \
    GLOAD_LDS16(gb__,          db__); \
    GLOAD_LDS16(gb__ + 16384,  db__ + 1024); \
    GLOAD_LDS16(gb__ + 32768,  db__ + 2048); \
    GLOAD_LDS16(gb__ + 49152,  db__ + 3072); \
  } while (0)

// load one j-chunk pair (rows j0*8.. and (j0+1)*8..) of tile tt into 4 float4
#define FLIGHT(fA0, fA1, fB0, fB1, j0, tt) do { \
    const float* p0__ = capA + (size_t)(j0) * 8192 + (tt) * 64; \
    const float* p1__ = p0__ + 8192; \
    fA0 = *reinterpret_cast<const float4*>(p0__); \
    fA1 = *reinterpret_cast<const float4*>(p0__ + 4); \
    fB0 = *reinterpret_cast<const float4*>(p1__); \
    fB1 = *reinterpret_cast<const float4*>(p1__ + 4); \
  } while (0)

// convert 8 floats -> 16B bf16, store to LDS (linear lane*16: conflict-free)
#define PACK_WRITE(fA, fB, wp) do { \
    short8 o__; \
    o__[0] = (short)f2b(fA.x); o__[1] = (short)f2b(fA.y); \
    o__[2] = (short)f2b(fA.z); o__[3] = (short)f2b(fA.w); \
    o__[4] = (short)f2b(fB.x); o__[5] = (short)f2b(fB.y); \
    o__[6] = (short)f2b(fB.z); o__[7] = (short)f2b(fB.w); \
    *reinterpret_cast<short8*>(wp) = o__; \
  } while (0)

#define DSREAD(dst, addr) \
  asm volatile("ds_read_b128 %0, %1" : "=v"(dst) : "v"(addr))

// read one A row-half rh (64 rows): 8 x ds_read_b128 into Areg
#define READ_A(rh) do { \
_Pragma("unroll") \
    for (int mf = 0; mf < 4; ++mf) \
_Pragma("unroll") \
      for (int ks = 0; ks < 2; ++ks) { \
        unsigned r__ = (unsigned)(wm * 128 + (rh) * 64 + mf * 16 + l15); \
        DSREAD(Areg[mf * 2 + ks], sA + r__ * 128 + (((unsigned)(ks * 64 + l4 * 16)) ^ swb)); \
      } \
  } while (0)

// read one B column-half (32 cols): 4 x ds_read_b128
#define READ_B(Breg, ch) do { \
_Pragma("unroll") \
    for (int nf = 0; nf < 2; ++nf) \
_Pragma("unroll") \
      for (int ks = 0; ks < 2; ++ks) { \
        unsigned c__ = (unsigned)(wn * 64 + (ch) * 32 + nf * 16 + l15); \
        DSREAD(Breg[nf * 2 + ks], sB + c__ * 128 + (((unsigned)(ks * 64 + l4 * 16)) ^ swb)); \
      } \
  } while (0)

// 16 MFMAs: row-half rh x column-half ch
#define MFMA16(rh, ch, Breg) do { \
    __builtin_amdgcn_s_setprio(1); \
_Pragma("unroll") \
    for (int mf = 0; mf < 4; ++mf) \
_Pragma("unroll") \
      for (int nf = 0; nf < 2; ++nf) \
_Pragma("unroll") \
        for (int ks = 0; ks < 2; ++ks) \
          acc[(rh) * 4 + mf][(ch) * 2 + nf] = __builtin_amdgcn_mfma_f32_16x16x32_bf16( \
              Areg[mf * 2 + ks], Breg[nf * 2 + ks], acc[(rh) * 4 + mf][(ch) * 2 + nf], 0, 0, 0); \
    __builtin_amdgcn_s_setprio(0); \
  } while (0)

#define WAIT_LGKM(n) do { \
    asm volatile("s_waitcnt lgkmcnt(" #n ")" ::: "memory"); \
    __builtin_amdgcn_sched_barrier(0); \
  } while (0)

#define BAR() asm volatile("s_barrier" ::: "memory")

  short8 Areg[8], B0reg[4], B1reg[4];
  float4 g0a, g0b, g1a, g1b;   // flight 1 (j-chunks 0,1)
  float4 g2a, g2b, g3a, g3b;   // flight 2 (j-chunks 2,3)

  // prologue: stage B(0) DMA + A(0) flights; drain; pack A(0) -> slot 0;
  // issue A(1) flights (packed at P1 of t=0); join.
  STAGE_B(0);
  FLIGHT(g0a, g0b, g1a, g1b, 0, 0);
  FLIGHT(g2a, g2b, g3a, g3b, 2, 0);
  asm volatile("s_waitcnt vmcnt(0)" ::: "memory");
  {
    unsigned char* wp = lds + wv * 4096 + lane * 16;   // A slot 0
    PACK_WRITE(g0a, g0b, wp);
    PACK_WRITE(g1a, g1b, wp + 1024);
    PACK_WRITE(g2a, g2b, wp + 2048);
    PACK_WRITE(g3a, g3b, wp + 3072);
  }
  FLIGHT(g0a, g0b, g1a, g1b, 0, 1);
  FLIGHT(g2a, g2b, g3a, g3b, 2, 1);
  WAIT_LGKM(0);
  BAR();

  for (int t = 0; t < 16; ++t) {
    const unsigned sA = ldsBase + (unsigned)((t & 1) * 65536);
    const unsigned sB = sA + 32768u;

    // ---- P0: A0 + B0 reads | BAR | lgkm(0) | MFMA(0,0) | BAR ----
    READ_A(0);
    READ_B(B0reg, 0);
    BAR();
    WAIT_LGKM(0);
    MFMA16(0, 0, B0reg);
    BAR();

    // ---- P1: B1 reads; vmcnt(0)+pack A(t+1); STAGE_B(t+1)
    //          | BAR | lgkm(4) | MFMA(0,1) | BAR ----
    READ_B(B1reg, 1);
    if (t < 15) {
      asm volatile("s_waitcnt vmcnt(0)" ::: "memory");   // flights from t-1
      __builtin_amdgcn_sched_barrier(0);
      unsigned char* wp = lds + ((t + 1) & 1) * 65536 + wv * 4096 + lane * 16;
      PACK_WRITE(g0a, g0b, wp);
      PACK_WRITE(g1a, g1b, wp + 1024);
      PACK_WRITE(g2a, g2b, wp + 2048);
      PACK_WRITE(g3a, g3b, wp + 3072);
      STAGE_B(t + 1);
    }
    BAR();
    if (t < 15) { WAIT_LGKM(4); }   // queue: [4 B1 reads][4 ds_writes]
    else        { WAIT_LGKM(0); }
    MFMA16(0, 1, B1reg);
    BAR();

    // ---- P2: A1 reads; flight1(t+2) | BAR | lgkm(0) | MFMA(1,0) | BAR ----
    READ_A(1);
    if (t < 14) FLIGHT(g0a, g0b, g1a, g1b, 0, t + 2);
    BAR();
    WAIT_LGKM(0);
    MFMA16(1, 0, B0reg);
    BAR();

    // ---- P3: flight2; counted vmcnt | BAR | MFMA(1,1) | BAR ----
    if (t < 14) FLIGHT(g2a, g2b, g3a, g3b, 2, t + 2);
    if (t < 15) {
      if (t < 14) {
        asm volatile("s_waitcnt vmcnt(8)" ::: "memory"); // drain B-DMA only
      } else {
        asm volatile("s_waitcnt vmcnt(0)" ::: "memory"); // t=14: only B-DMA left
      }
      __builtin_amdgcn_sched_barrier(0);
    }
    BAR();
    MFMA16(1, 1, B1reg);
    if (t < 15) BAR();
  }

  // epilogue: s[m] = sum_n tanh(acc + colb[n]) * Wa[n], reduce over l15
  float colb[4], wav[4];
#pragma unroll
  for (int nf = 0; nf < 4; ++nf) {
    int cg = n0 + wn * 64 + nf * 16 + l15;
    colb[nf] = att2pre[bb * 1024 + cg] + bfv[cg] + bdv[cg];
    wav[nf]  = Wa[cg];
  }
#pragma unroll
  for (int mf = 0; mf < 8; ++mf) {
#pragma unroll
    for (int r = 0; r < 4; ++r) {
      float s = tanh_fast(acc[mf][0][r] + colb[0]) * wav[0]
              + tanh_fast(acc[mf][1][r] + colb[1]) * wav[1]
              + tanh_fast(acc[mf][2][r] + colb[2]) * wav[2]
              + tanh_fast(acc[mf][3][r] + colb[3]) * wav[3];
      s += __shfl_xor(s, 1);
      s += __shfl_xor(s, 2);
      s += __shfl_xor(s, 4);
      s += __shfl_xor(s, 8);
      if (l15 == 0)
        atomicAdd(scores + (m0 + wm * 128 + mf * 16 + l4 * 4 + r), s);
    }
  }
#undef STAGE_B
#undef FLIGHT
#undef PACK_WRITE
#undef DSREAD
#undef READ_A
#undef READ_B
#undef MFMA16
#undef WAIT_LGKM
#undef BAR
}

// ---------------------------------------------------------------------------
__global__ __launch_bounds__(256) void softmax_k(
    const float* __restrict__ scores, const int* __restrict__ mask,
    float* __restrict__ alpha)
{
  const int b = blockIdx.x, tid = threadIdx.x;
  __shared__ float red[8];
  float s[4];
  float mx = -3.0e38f;
#pragma unroll
  for (int i = 0; i < 4; ++i) {
    int l = tid + i * 256;
    float v = scores[b * 1024 + l];
    v = (mask[b * 1024 + l] == 0) ? -1.0e10f : v;
    s[i] = v;
    mx = fmaxf(mx, v);
  }
  for (int off = 1; off < 64; off <<= 1) mx = fmaxf(mx, __shfl_xor(mx, off));
  int wv = tid >> 6;
  if ((tid & 63) == 0) red[wv] = mx;
  __syncthreads();
  mx = fmaxf(fmaxf(red[0], red[1]), fmaxf(red[2], red[3]));
  float sum = 0.f;
#pragma unroll
  for (int i = 0; i < 4; ++i) {
    s[i] = exp2f_fast((s[i] - mx) * LOG2E);
    sum += s[i];
  }
  for (int off = 1; off < 64; off <<= 1) sum += __shfl_xor(sum, off);
  if ((tid & 63) == 0) red[4 + wv] = sum;
  __syncthreads();
  sum = red[4] + red[5] + red[6] + red[7];
  float inv = 1.0f / sum;
#pragma unroll
  for (int i = 0; i < 4; ++i) alpha[b * 1024 + tid + i * 256] = s[i] * inv;
}

// ---------------------------------------------------------------------------
// ctx_kb: reads cap f32 directly
// ---------------------------------------------------------------------------
__global__ __launch_bounds__(256) void ctx_kb(
    const float* __restrict__ cap, const float* __restrict__ alpha,
    float* __restrict__ ctx)
{
  const int b = blockIdx.y, lc = blockIdx.x;
  const int dc = threadIdx.x & 127, loff = threadIdx.x >> 7;
  float acc[8] = {0.f, 0.f, 0.f, 0.f, 0.f, 0.f, 0.f, 0.f};
  for (int l = lc * 128 + loff; l < lc * 128 + 128; l += 2) {
    float av = alpha[b * 1024 + l];
    if (av != 0.f) {
      const float* p = cap + (((size_t)(b * 1024 + l)) << 10) + dc * 8;
      float4 v0 = *reinterpret_cast<const float4*>(p);
      float4 v1 = *reinterpret_cast<const float4*>(p + 4);
      acc[0] += av * v0.x; acc[1] += av * v0.y;
      acc[2] += av * v0.z; acc[3] += av * v0.w;
      acc[4] += av * v1.x; acc[5] += av * v1.y;
      acc[6] += av * v1.z; acc[7] += av * v1.w;
    }
  }
#pragma unroll
  for (int j = 0; j < 8; ++j) atomicAdd(ctx + b * 1024 + dc * 8 + j, acc[j]);
}

// ---------------------------------------------------------------------------
__global__ __launch_bounds__(256) void final_k(
    const float* __restrict__ ztp, const float* __restrict__ scp,
    const float* __restrict__ tcp, const float* __restrict__ bg,
    const float* __restrict__ bs, const float* __restrict__ bt,
    float* __restrict__ out)
{
  const int idx = blockIdx.x * 256 + threadIdx.x;
  const int d = idx & 1023;
  float z  = rcp_fast(1.0f + exp2f_fast(-(ztp[idx] + bg[d]) * LOG2E));
  float sc = tanh_fast(scp[idx] + bs[d]);
  float tc = tanh_fast(tcp[idx] + bt[d]);
  out[idx] = z * sc + (1.0f - z) * tc;
}

extern "C" void kernel_launch(void* const* d_in, const int* in_sizes, int n_in,
                              void* d_out, int out_size, void* d_ws, size_t ws_size,
                              hipStream_t stream) {
  const float* cap  = (const float*)d_in[0];
  const float* dh   = (const float*)d_in[1];
  const float* word = (const float*)d_in[2];
  const int*   mask = (const int*)d_in[3];
  const float* Wf   = (const float*)d_in[4];
  const float* bf   = (const float*)d_in[5];
  const float* Wd   = (const float*)d_in[6];
  const float* bd   = (const float*)d_in[7];
  const float* Wa   = (const float*)d_in[8];
  // d_in[9] = ba: softmax-invariant, dropped.
  const float* Wg   = (const float*)d_in[10];
  const float* bg   = (const float*)d_in[11];
  const float* Ws   = (const float*)d_in[12];
  const float* bs   = (const float*)d_in[13];
  const float* Wt   = (const float*)d_in[14];
  const float* bt   = (const float*)d_in[15];

  float* out_g = (float*)d_out;            // (32,1024) gated_context
  float* alpha = (float*)d_out + 32768;    // (32,1024) alpha

  float* att2pre = (float*)d_ws;           // 6 x 32768 f32 (zeroed)
  float* scores  = att2pre + 32768;
  float* ctx     = scores + 32768;
  float* ztp     = ctx + 32768;
  float* scp     = ztp + 32768;
  float* tcp     = scp + 32768;
  unsigned short* wfb = (unsigned short*)((char*)d_ws + 786432);  // 2 MB

  hipMemsetAsync(d_ws, 0, 6 * 32768 * sizeof(float), stream);

  convert_att2<<<208, 256, 0, stream>>>(Wf, wfb, Wd, dh, att2pre,
                                        Wg, Wt, word, ztp, tcp);
  att_gemm3<<<512, 512, 0, stream>>>(cap, wfb, att2pre, bf, bd, Wa, scores);
  softmax_k<<<32, 256, 0, stream>>>(scores, mask, alpha);
  ctx_kb<<<dim3(8, 32), 256, 0, stream>>>(cap, alpha, ctx);
  gate_gemm<<<dim3(8, 4), 256, 0, stream>>>(Wg, Ws, word, dh, ctx, ztp, scp);
  final_k<<<128, 256, 0, stream>>>(ztp, scp, tcp, bg, bs, bt, out_g);
}

// Round 10
// 157.787 us; speedup vs baseline: 1.0619x; 1.0619x over previous
//
#include <hip/hip_runtime.h>
#include <hip/hip_bf16.h>
#include <cstdint>
#include <cstddef>

#define LOG2E 1.4426950408889634f

typedef __attribute__((ext_vector_type(8))) short short8;
typedef __attribute__((ext_vector_type(4))) float f32x4;

__device__ __forceinline__ float exp2f_fast(float x) { return __builtin_amdgcn_exp2f(x); }
__device__ __forceinline__ float rcp_fast(float x)   { return __builtin_amdgcn_rcpf(x); }
__device__ __forceinline__ float tanh_fast(float x) {
  float e = exp2f_fast(x * (2.0f * LOG2E));
  return 1.0f - 2.0f * rcp_fast(e + 1.0f);
}
__device__ __forceinline__ unsigned short f2b(float f) {  // f32 -> bf16 RNE
  union { float f; unsigned int u; } v; v.f = f;
  return (unsigned short)((v.u + 0x7FFFu + ((v.u >> 16) & 1u)) >> 16);
}
__device__ __forceinline__ float b2f(short h) {
  union { unsigned u; float f; } w; w.u = ((unsigned)(unsigned short)h) << 16;
  return w.f;
}

#define GLOAD_LDS16(g, l) \
  __builtin_amdgcn_global_load_lds((const __attribute__((address_space(1))) unsigned int*)(g), \
                                   (__attribute__((address_space(3))) unsigned int*)(l), 16, 0, 0)

// ---------------------------------------------------------------------------
// Skinny MFMA GEMM helper (M=32): out[b, n0..n0+127] += X @ W^T
// ---------------------------------------------------------------------------
__device__ __forceinline__ void skinny_gemm(
    const float* __restrict__ W, int Kfull,
    const float* __restrict__ x0, const float* __restrict__ x1,
    const float* __restrict__ x2,
    int kbeg, int kend, int n0, float* __restrict__ out)
{
  __shared__ unsigned char sX[4096];   // 32 rows x 64 k bf16, XOR-swizzled
  const int tid = threadIdx.x, lane = tid & 63, wv = tid >> 6;
  const int l15 = lane & 15, l4 = lane >> 4;
  f32x4 acc[2][2];
#pragma unroll
  for (int m = 0; m < 2; ++m)
#pragma unroll
    for (int j = 0; j < 2; ++j) acc[m][j] = (f32x4){0.f, 0.f, 0.f, 0.f};

  const int srow = tid >> 3, skc = (tid & 7) * 8;
  const int sbyte = srow * 128 + ((skc * 2) ^ ((srow & 7) << 4));

  for (int k0 = kbeg; k0 < kend; k0 += 64) {
    const float* xs = (k0 < 1024) ? x0 : (k0 < 2048) ? x1 : x2;
    const float* xp = xs + srow * 1024 + (k0 & 1023) + skc;
    float4 a = *reinterpret_cast<const float4*>(xp);
    float4 b = *reinterpret_cast<const float4*>(xp + 4);
    short8 h;
    h[0] = (short)f2b(a.x); h[1] = (short)f2b(a.y); h[2] = (short)f2b(a.z); h[3] = (short)f2b(a.w);
    h[4] = (short)f2b(b.x); h[5] = (short)f2b(b.y); h[6] = (short)f2b(b.z); h[7] = (short)f2b(b.w);
    *reinterpret_cast<short8*>(sX + sbyte) = h;
    __syncthreads();
#pragma unroll
    for (int ks = 0; ks < 2; ++ks) {
      short8 af[2], bfr[2];
#pragma unroll
      for (int m = 0; m < 2; ++m) {
        int r = m * 16 + l15;
        af[m] = *reinterpret_cast<const short8*>(
            sX + r * 128 + (((ks * 64) + l4 * 16) ^ ((r & 7) << 4)));
      }
#pragma unroll
      for (int j = 0; j < 2; ++j) {
        int n = n0 + wv * 32 + j * 16 + l15;
        const float* wp = W + (size_t)n * Kfull + k0 + ks * 32 + l4 * 8;
        float4 wa = *reinterpret_cast<const float4*>(wp);
        float4 wb = *reinterpret_cast<const float4*>(wp + 4);
        short8 hb;
        hb[0] = (short)f2b(wa.x); hb[1] = (short)f2b(wa.y); hb[2] = (short)f2b(wa.z); hb[3] = (short)f2b(wa.w);
        hb[4] = (short)f2b(wb.x); hb[5] = (short)f2b(wb.y); hb[6] = (short)f2b(wb.z); hb[7] = (short)f2b(wb.w);
        bfr[j] = hb;
      }
#pragma unroll
      for (int m = 0; m < 2; ++m)
#pragma unroll
        for (int j = 0; j < 2; ++j)
          acc[m][j] = __builtin_amdgcn_mfma_f32_16x16x32_bf16(af[m], bfr[j], acc[m][j], 0, 0, 0);
    }
    __syncthreads();
  }
#pragma unroll
  for (int m = 0; m < 2; ++m)
#pragma unroll
    for (int j = 0; j < 2; ++j)
#pragma unroll
      for (int r = 0; r < 4; ++r)
        atomicAdd(out + (size_t)(m * 16 + l4 * 4 + r) * 1024 + (n0 + wv * 32 + j * 16 + l15),
                  acc[m][j][r]);
}

// ---------------------------------------------------------------------------
// convert_att2 v4: only Wf->bf16 (2 MB) + att2pre skinny gemm.
//   [0,128)    Wf convert
//   [128,144)  att2pre skinny gemm
// ---------------------------------------------------------------------------
__global__ __launch_bounds__(256) void convert_att2(
    const float* __restrict__ wf, unsigned short* __restrict__ wfb,
    const float* __restrict__ Wd, const float* __restrict__ dh,
    float* __restrict__ att2)
{
  const int bid = blockIdx.x;
  if (bid < 128) {
    const int base = bid * 1024;
#pragma unroll
    for (int j = 0; j < 4; ++j) {
      int g = base + j * 256 + (int)threadIdx.x;
      const float* s = wf + (size_t)g * 8;
      float4 a = *reinterpret_cast<const float4*>(s);
      float4 b = *reinterpret_cast<const float4*>(s + 4);
      short8 o;
      o[0] = (short)f2b(a.x); o[1] = (short)f2b(a.y); o[2] = (short)f2b(a.z); o[3] = (short)f2b(a.w);
      o[4] = (short)f2b(b.x); o[5] = (short)f2b(b.y); o[6] = (short)f2b(b.z); o[7] = (short)f2b(b.w);
      *reinterpret_cast<short8*>(wfb + (size_t)g * 8) = o;
    }
  } else {
    int bid2 = bid - 128;
    int nt = bid2 & 7, ks = bid2 >> 3;
    skinny_gemm(Wd, 1024, dh, dh, dh, ks * 512, ks * 512 + 512, nt * 128, att2);
  }
}

// ---------------------------------------------------------------------------
// Gate GEMMs (R5 12-slot form)
// ---------------------------------------------------------------------------
__global__ __launch_bounds__(256) void gate_gemm(
    const float* __restrict__ Wg, const float* __restrict__ Ws_,
    const float* __restrict__ Wt, const float* __restrict__ word,
    const float* __restrict__ dh, const float* __restrict__ ctx,
    float* __restrict__ ztp, float* __restrict__ scp, float* __restrict__ tcp)
{
  const int nt = blockIdx.x, slot = blockIdx.y;
  if (slot < 6)
    skinny_gemm(Wg, 3072, word, dh, ctx, slot * 512, slot * 512 + 512, nt * 128, ztp);
  else if (slot < 8)
    skinny_gemm(Ws_, 1024, ctx, ctx, ctx, (slot - 6) * 512, (slot - 6) * 512 + 512, nt * 128, scp);
  else
    skinny_gemm(Wt, 2048, word, dh, dh, (slot - 8) * 512, (slot - 8) * 512 + 512, nt * 128, tcp);
}

// ---------------------------------------------------------------------------
// att_gemm3 v5 (best-measured: 104.7-109 us): fused A-conversion with
// CROSS-BARRIER register staging. Flights issued late in tile t hold
// A-tile (t+2)'s f32 data; converted + ds_written at the TOP of tile t+1
// into slot (t+2)&1. Every vmem wait has >= 1 tile of cover:
//   top of tile t:  vmcnt(0) drains flights issued in t-1 (~2500 cyc ago)
//   end of tile t:  vmcnt(8) leaves the 8 flights in flight, drains only
//                   STAGE_B(t+1) DMA (issued at tile top, full-tile cover)
// A is time-triple-buffered over the 2 LDS slots. 1 barrier per K-tile.
// NOTE: 128 VGPR + 128 acc = 256 unified regs -> exactly 2 waves/SIMD;
// any register growth halves occupancy (measured cliff).
// ---------------------------------------------------------------------------
__global__ __launch_bounds__(512, 2) void att_gemm3(
    const float* __restrict__ cap, const unsigned short* __restrict__ wfb,
    const float* __restrict__ att2pre, const float* __restrict__ bfv,
    const float* __restrict__ bdv, const float* __restrict__ Wa,
    float* __restrict__ scores)
{
  __shared__ __align__(16) unsigned char lds[131072];   // 2 slots x (A 32K + B 32K)
  const int tid = threadIdx.x, lane = tid & 63, wv = tid >> 6;
  // bijective XCD chunking: nwg=512, 8 XCDs, 64 jobs/XCD
  const int j = ((int)blockIdx.x & 7) * 64 + ((int)blockIdx.x >> 3);
  const int mt = j >> 2, nt = j & 3;            // 128 m-tiles x 4 n-tiles
  const int m0 = mt << 8, n0 = nt << 8;
  const int bb = m0 >> 10;                      // batch (256 | 1024)
  const int wm = wv >> 2, wn = wv & 3;          // 2M x 4N
  const int l15 = lane & 15, l4 = lane >> 4;
  const int r8 = lane >> 3, c8 = lane & 7;
  const unsigned swb = (unsigned)((l15 & 7) << 4);

  // A staging source: f32, inverse-swizzled column (bf16 byte off / 2).
  const float* capA = cap + (size_t)(m0 + wv * 32 + r8) * 1024 +
                      ((unsigned)((c8 * 16) ^ (r8 << 4)) >> 1);
  // B stage source (bf16 wfb, DMA path)
  const unsigned char* bSrc = (const unsigned char*)wfb +
      (size_t)(n0 + wv * 32 + r8) * 2048 + ((c8 * 16) ^ (r8 << 4));
  const unsigned ldsBase = (unsigned)(size_t)(&lds[0]);

  f32x4 acc[8][4];
#pragma unroll
  for (int mf = 0; mf < 8; ++mf)
#pragma unroll
    for (int nf = 0; nf < 4; ++nf) acc[mf][nf] = (f32x4){0.f, 0.f, 0.f, 0.f};

#define STAGE_B(t) do { \
    const int sl__ = (t) & 1; \
    unsigned char* db__ = lds + sl__ * 65536 + 32768 + wv * 4096; \
    const unsigned char* gb__ = bSrc + (t) * 128; \
    GLOAD_LDS16(gb__,          db__); \
    GLOAD_LDS16(gb__ + 16384,  db__ + 1024); \
    GLOAD_LDS16(gb__ + 32768,  db__ + 2048); \
    GLOAD_LDS16(gb__ + 49152,  db__ + 3072); \
  } while (0)

// load one j-chunk pair (rows j0*8.. and (j0+1)*8..) of tile tt into 4 float4
#define FLIGHT(fA0, fA1, fB0, fB1, j0, tt) do { \
    const float* p0__ = capA + (size_t)(j0) * 8192 + (tt) * 64; \
    const float* p1__ = p0__ + 8192; \
    fA0 = *reinterpret_cast<const float4*>(p0__); \
    fA1 = *reinterpret_cast<const float4*>(p0__ + 4); \
    fB0 = *reinterpret_cast<const float4*>(p1__); \
    fB1 = *reinterpret_cast<const float4*>(p1__ + 4); \
  } while (0)

// convert 8 floats -> 16B bf16, store to LDS (linear lane*16: conflict-free)
#define PACK_WRITE(fA, fB, wp) do { \
    short8 o__; \
    o__[0] = (short)f2b(fA.x); o__[1] = (short)f2b(fA.y); \
    o__[2] = (short)f2b(fA.z); o__[3] = (short)f2b(fA.w); \
    o__[4] = (short)f2b(fB.x); o__[5] = (short)f2b(fB.y); \
    o__[6] = (short)f2b(fB.z); o__[7] = (short)f2b(fB.w); \
    *reinterpret_cast<short8*>(wp) = o__; \
  } while (0)

#define DSREAD(dst, addr) \
  asm volatile("ds_read_b128 %0, %1" : "=v"(dst) : "v"(addr))

// read one A quarter (32 rows): 4 x ds_read_b128 into dst[0..3]
#define READ_AQ(dst, q) do { \
_Pragma("unroll") \
    for (int mf2 = 0; mf2 < 2; ++mf2) \
_Pragma("unroll") \
      for (int ks = 0; ks < 2; ++ks) { \
        unsigned r__ = (unsigned)(wm * 128 + (q) * 32 + mf2 * 16 + l15); \
        DSREAD(dst[mf2 * 2 + ks], sA + r__ * 128 + (((unsigned)(ks * 64 + l4 * 16)) ^ swb)); \
      } \
  } while (0)

// read one B column-half (32 cols): 4 x ds_read_b128 into Breg[ch*4 ..]
#define READ_B(ch) do { \
_Pragma("unroll") \
    for (int nf = 0; nf < 2; ++nf) \
_Pragma("unroll") \
      for (int ks = 0; ks < 2; ++ks) { \
        unsigned c__ = (unsigned)(wn * 64 + (ch) * 32 + nf * 16 + l15); \
        DSREAD(Breg[(ch) * 4 + nf * 2 + ks], sB + c__ * 128 + (((unsigned)(ks * 64 + l4 * 16)) ^ swb)); \
      } \
  } while (0)

// 8 MFMAs: quarter q (rows q*32..+31) x column-half ch (cols ch*32..+31)
#define MFMA8(q, ch, Aq) do { \
    __builtin_amdgcn_s_setprio(1); \
_Pragma("unroll") \
    for (int mf2 = 0; mf2 < 2; ++mf2) \
_Pragma("unroll") \
      for (int nf = 0; nf < 2; ++nf) \
_Pragma("unroll") \
        for (int ks = 0; ks < 2; ++ks) \
          acc[(q) * 2 + mf2][(ch) * 2 + nf] = __builtin_amdgcn_mfma_f32_16x16x32_bf16( \
              Aq[mf2 * 2 + ks], Breg[(ch) * 4 + nf * 2 + ks], acc[(q) * 2 + mf2][(ch) * 2 + nf], 0, 0, 0); \
    __builtin_amdgcn_s_setprio(0); \
  } while (0)

#define WAIT_LGKM(n) do { \
    asm volatile("s_waitcnt lgkmcnt(" #n ")" ::: "memory"); \
    __builtin_amdgcn_sched_barrier(0); \
  } while (0)

  short8 Aq0[4], Aq1[4], Breg[8];
  float4 g0a, g0b, g1a, g1b;   // flight 1 (j-chunks 0,1)
  float4 g2a, g2b, g3a, g3b;   // flight 2 (j-chunks 2,3)

  // prologue: stage B(0) DMA + A(0) flights; drain; pack A(0) -> slot 0;
  // issue A(1) flights (held in regs, packed at top of t=0); join.
  STAGE_B(0);
  FLIGHT(g0a, g0b, g1a, g1b, 0, 0);
  FLIGHT(g2a, g2b, g3a, g3b, 2, 0);
  asm volatile("s_waitcnt vmcnt(0)" ::: "memory");
  {
    unsigned char* wp = lds + wv * 4096 + lane * 16;   // A slot 0
    PACK_WRITE(g0a, g0b, wp);
    PACK_WRITE(g1a, g1b, wp + 1024);
    PACK_WRITE(g2a, g2b, wp + 2048);
    PACK_WRITE(g3a, g3b, wp + 3072);
  }
  FLIGHT(g0a, g0b, g1a, g1b, 0, 1);
  FLIGHT(g2a, g2b, g3a, g3b, 2, 1);
  WAIT_LGKM(0);
  asm volatile("s_barrier" ::: "memory");

  for (int t = 0; t < 16; ++t) {
    const unsigned sA = ldsBase + (unsigned)((t & 1) * 65536);
    const unsigned sB = sA + 32768u;

    // (1) pack A(t+1) from flights issued in tile t-1 (full-tile cover)
    if (t < 15) {
      asm volatile("s_waitcnt vmcnt(0)" ::: "memory");
      __builtin_amdgcn_sched_barrier(0);
      unsigned char* wp = lds + ((t + 1) & 1) * 65536 + wv * 4096 + lane * 16;
      PACK_WRITE(g0a, g0b, wp);
      PACK_WRITE(g1a, g1b, wp + 1024);
      PACK_WRITE(g2a, g2b, wp + 2048);
      PACK_WRITE(g3a, g3b, wp + 3072);
    }
    // (2) stage B(t+1) via DMA (drained at end-of-tile wait)
    if (t < 15) STAGE_B(t + 1);

    // (3) read bursts for tile t (ds queue: [4 writes] + 16 reads)
    READ_AQ(Aq0, 0);
    READ_B(0);
    READ_B(1);
    READ_AQ(Aq1, 1);

    // (4) quarter-pipelined MFMA schedule (R2-proven)
    WAIT_LGKM(8);                       // writes + AQ0 + B(ch0) done
    MFMA8(0, 0, Aq0);
    WAIT_LGKM(4);                       // + B(ch1) done
    MFMA8(0, 1, Aq0);
    WAIT_LGKM(0);                       // + AQ1 done
    READ_AQ(Aq0, 2);                    // prefetch q2 (reuse Aq0)
    MFMA8(1, 0, Aq1);
    MFMA8(1, 1, Aq1);
    READ_AQ(Aq1, 3);                    // prefetch q3
    WAIT_LGKM(4);                       // AQ2 done (AQ3 in flight)
    MFMA8(2, 0, Aq0);
    MFMA8(2, 1, Aq0);
    // (5) flights for A(t+2): issued here, packed at top of t+1
    if (t < 14) FLIGHT(g0a, g0b, g1a, g1b, 0, t + 2);
    WAIT_LGKM(0);                       // AQ3 done
    MFMA8(3, 0, Aq1);
    MFMA8(3, 1, Aq1);
    if (t < 14) FLIGHT(g2a, g2b, g3a, g3b, 2, t + 2);

    // (6) end: drain only B-DMA (keep flights in flight), join
    if (t < 15) {
      if (t < 14) {
        asm volatile("s_waitcnt vmcnt(8)" ::: "memory");  // leave 8 flights
      } else {
        asm volatile("s_waitcnt vmcnt(0)" ::: "memory");  // only B DMA left
      }
      asm volatile("s_barrier" ::: "memory");
    }
  }

  // epilogue: s[m] = sum_n tanh(acc + colb[n]) * Wa[n], reduce over l15
  float colb[4], wav[4];
#pragma unroll
  for (int nf = 0; nf < 4; ++nf) {
    int cg = n0 + wn * 64 + nf * 16 + l15;
    colb[nf] = att2pre[bb * 1024 + cg] + bfv[cg] + bdv[cg];
    wav[nf]  = Wa[cg];
  }
#pragma unroll
  for (int mf = 0; mf < 8; ++mf) {
#pragma unroll
    for (int r = 0; r < 4; ++r) {
      float s = tanh_fast(acc[mf][0][r] + colb[0]) * wav[0]
              + tanh_fast(acc[mf][1][r] + colb[1]) * wav[1]
              + tanh_fast(acc[mf][2][r] + colb[2]) * wav[2]
              + tanh_fast(acc[mf][3][r] + colb[3]) * wav[3];
      s += __shfl_xor(s, 1);
      s += __shfl_xor(s, 2);
      s += __shfl_xor(s, 4);
      s += __shfl_xor(s, 8);
      if (l15 == 0)
        atomicAdd(scores + (m0 + wm * 128 + mf * 16 + l4 * 4 + r), s);
    }
  }
#undef STAGE_B
#undef FLIGHT
#undef PACK_WRITE
#undef DSREAD
#undef READ_AQ
#undef READ_B
#undef MFMA8
#undef WAIT_LGKM
}

// ---------------------------------------------------------------------------
__global__ __launch_bounds__(256) void softmax_k(
    const float* __restrict__ scores, const int* __restrict__ mask,
    float* __restrict__ alpha)
{
  const int b = blockIdx.x, tid = threadIdx.x;
  __shared__ float red[8];
  float s[4];
  float mx = -3.0e38f;
#pragma unroll
  for (int i = 0; i < 4; ++i) {
    int l = tid + i * 256;
    float v = scores[b * 1024 + l];
    v = (mask[b * 1024 + l] == 0) ? -1.0e10f : v;
    s[i] = v;
    mx = fmaxf(mx, v);
  }
  for (int off = 1; off < 64; off <<= 1) mx = fmaxf(mx, __shfl_xor(mx, off));
  int wv = tid >> 6;
  if ((tid & 63) == 0) red[wv] = mx;
  __syncthreads();
  mx = fmaxf(fmaxf(red[0], red[1]), fmaxf(red[2], red[3]));
  float sum = 0.f;
#pragma unroll
  for (int i = 0; i < 4; ++i) {
    s[i] = exp2f_fast((s[i] - mx) * LOG2E);
    sum += s[i];
  }
  for (int off = 1; off < 64; off <<= 1) sum += __shfl_xor(sum, off);
  if ((tid & 63) == 0) red[4 + wv] = sum;
  __syncthreads();
  sum = red[4] + red[5] + red[6] + red[7];
  float inv = 1.0f / sum;
#pragma unroll
  for (int i = 0; i < 4; ++i) alpha[b * 1024 + tid + i * 256] = s[i] * inv;
}

// ---------------------------------------------------------------------------
// ctx_kb: reads cap f32 directly (capb eliminated)
// ---------------------------------------------------------------------------
__global__ __launch_bounds__(256) void ctx_kb(
    const float* __restrict__ cap, const float* __restrict__ alpha,
    float* __restrict__ ctx)
{
  const int b = blockIdx.y, lc = blockIdx.x;
  const int dc = threadIdx.x & 127, loff = threadIdx.x >> 7;
  float acc[8] = {0.f, 0.f, 0.f, 0.f, 0.f, 0.f, 0.f, 0.f};
  for (int l = lc * 128 + loff; l < lc * 128 + 128; l += 2) {
    float av = alpha[b * 1024 + l];
    if (av != 0.f) {
      const float* p = cap + (((size_t)(b * 1024 + l)) << 10) + dc * 8;
      float4 v0 = *reinterpret_cast<const float4*>(p);
      float4 v1 = *reinterpret_cast<const float4*>(p + 4);
      acc[0] += av * v0.x; acc[1] += av * v0.y;
      acc[2] += av * v0.z; acc[3] += av * v0.w;
      acc[4] += av * v1.x; acc[5] += av * v1.y;
      acc[6] += av * v1.z; acc[7] += av * v1.w;
    }
  }
#pragma unroll
  for (int j = 0; j < 8; ++j) atomicAdd(ctx + b * 1024 + dc * 8 + j, acc[j]);
}

// ---------------------------------------------------------------------------
__global__ __launch_bounds__(256) void final_k(
    const float* __restrict__ ztp, const float* __restrict__ scp,
    const float* __restrict__ tcp, const float* __restrict__ bg,
    const float* __restrict__ bs, const float* __restrict__ bt,
    float* __restrict__ out)
{
  const int idx = blockIdx.x * 256 + threadIdx.x;
  const int d = idx & 1023;
  float z  = rcp_fast(1.0f + exp2f_fast(-(ztp[idx] + bg[d]) * LOG2E));
  float sc = tanh_fast(scp[idx] + bs[d]);
  float tc = tanh_fast(tcp[idx] + bt[d]);
  out[idx] = z * sc + (1.0f - z) * tc;
}

extern "C" void kernel_launch(void* const* d_in, const int* in_sizes, int n_in,
                              void* d_out, int out_size, void* d_ws, size_t ws_size,
                              hipStream_t stream) {
  const float* cap  = (const float*)d_in[0];
  const float* dh   = (const float*)d_in[1];
  const float* word = (const float*)d_in[2];
  const int*   mask = (const int*)d_in[3];
  const float* Wf   = (const float*)d_in[4];
  const float* bf   = (const float*)d_in[5];
  const float* Wd   = (const float*)d_in[6];
  const float* bd   = (const float*)d_in[7];
  const float* Wa   = (const float*)d_in[8];
  // d_in[9] = ba: softmax-invariant, dropped.
  const float* Wg   = (const float*)d_in[10];
  const float* bg   = (const float*)d_in[11];
  const float* Ws   = (const float*)d_in[12];
  const float* bs   = (const float*)d_in[13];
  const float* Wt   = (const float*)d_in[14];
  const float* bt   = (const float*)d_in[15];

  float* out_g = (float*)d_out;            // (32,1024) gated_context
  float* alpha = (float*)d_out + 32768;    // (32,1024) alpha

  float* att2pre = (float*)d_ws;           // 6 x 32768 f32 (zeroed)
  float* scores  = att2pre + 32768;
  float* ctx     = scores + 32768;
  float* ztp     = ctx + 32768;
  float* scp     = ztp + 32768;
  float* tcp     = scp + 32768;
  unsigned short* wfb = (unsigned short*)((char*)d_ws + 786432);  // 2 MB

  hipMemsetAsync(d_ws, 0, 6 * 32768 * sizeof(float), stream);

  convert_att2<<<144, 256, 0, stream>>>(Wf, wfb, Wd, dh, att2pre);
  att_gemm3<<<512, 512, 0, stream>>>(cap, wfb, att2pre, bf, bd, Wa, scores);
  softmax_k<<<32, 256, 0, stream>>>(scores, mask, alpha);
  ctx_kb<<<dim3(8, 32), 256, 0, stream>>>(cap, alpha, ctx);
  gate_gemm<<<dim3(8, 12), 256, 0, stream>>>(Wg, Ws, Wt, word, dh, ctx, ztp, scp, tcp);
  final_k<<<128, 256, 0, stream>>>(ztp, scp, tcp, bg, bs, bt, out_g);
}

// Round 11
// 144.035 us; speedup vs baseline: 1.1633x; 1.0955x over previous
//
#include <hip/hip_runtime.h>
#include <hip/hip_bf16.h>
#include <cstdint>
#include <cstddef>

#define LOG2E 1.4426950408889634f

typedef __attribute__((ext_vector_type(8))) short short8;
typedef __attribute__((ext_vector_type(4))) float f32x4;

__device__ __forceinline__ float exp2f_fast(float x) { return __builtin_amdgcn_exp2f(x); }
__device__ __forceinline__ float rcp_fast(float x)   { return __builtin_amdgcn_rcpf(x); }
__device__ __forceinline__ float tanh_fast(float x) {
  float e = exp2f_fast(x * (2.0f * LOG2E));
  return 1.0f - 2.0f * rcp_fast(e + 1.0f);
}
__device__ __forceinline__ unsigned short f2b(float f) {  // f32 -> bf16 RNE
  union { float f; unsigned int u; } v; v.f = f;
  return (unsigned short)((v.u + 0x7FFFu + ((v.u >> 16) & 1u)) >> 16);
}
__device__ __forceinline__ float b2f(short h) {
  union { unsigned u; float f; } w; w.u = ((unsigned)(unsigned short)h) << 16;
  return w.f;
}

#define GLOAD_LDS16(g, l) \
  __builtin_amdgcn_global_load_lds((const __attribute__((address_space(1))) unsigned int*)(g), \
                                   (__attribute__((address_space(3))) unsigned int*)(l), 16, 0, 0)

// ---------------------------------------------------------------------------
// Skinny MFMA GEMM helper (M=32): out[b, n0..n0+127] += X @ W^T
// Works for any [kbeg,kend) aligned to 64 (x-operand chosen by global k).
// ---------------------------------------------------------------------------
__device__ __forceinline__ void skinny_gemm(
    const float* __restrict__ W, int Kfull,
    const float* __restrict__ x0, const float* __restrict__ x1,
    const float* __restrict__ x2,
    int kbeg, int kend, int n0, float* __restrict__ out)
{
  __shared__ unsigned char sX[4096];   // 32 rows x 64 k bf16, XOR-swizzled
  const int tid = threadIdx.x, lane = tid & 63, wv = tid >> 6;
  const int l15 = lane & 15, l4 = lane >> 4;
  f32x4 acc[2][2];
#pragma unroll
  for (int m = 0; m < 2; ++m)
#pragma unroll
    for (int j = 0; j < 2; ++j) acc[m][j] = (f32x4){0.f, 0.f, 0.f, 0.f};

  const int srow = tid >> 3, skc = (tid & 7) * 8;
  const int sbyte = srow * 128 + ((skc * 2) ^ ((srow & 7) << 4));

  for (int k0 = kbeg; k0 < kend; k0 += 64) {
    const float* xs = (k0 < 1024) ? x0 : (k0 < 2048) ? x1 : x2;
    const float* xp = xs + srow * 1024 + (k0 & 1023) + skc;
    float4 a = *reinterpret_cast<const float4*>(xp);
    float4 b = *reinterpret_cast<const float4*>(xp + 4);
    short8 h;
    h[0] = (short)f2b(a.x); h[1] = (short)f2b(a.y); h[2] = (short)f2b(a.z); h[3] = (short)f2b(a.w);
    h[4] = (short)f2b(b.x); h[5] = (short)f2b(b.y); h[6] = (short)f2b(b.z); h[7] = (short)f2b(b.w);
    *reinterpret_cast<short8*>(sX + sbyte) = h;
    __syncthreads();
#pragma unroll
    for (int ks = 0; ks < 2; ++ks) {
      short8 af[2], bfr[2];
#pragma unroll
      for (int m = 0; m < 2; ++m) {
        int r = m * 16 + l15;
        af[m] = *reinterpret_cast<const short8*>(
            sX + r * 128 + (((ks * 64) + l4 * 16) ^ ((r & 7) << 4)));
      }
#pragma unroll
      for (int j = 0; j < 2; ++j) {
        int n = n0 + wv * 32 + j * 16 + l15;
        const float* wp = W + (size_t)n * Kfull + k0 + ks * 32 + l4 * 8;
        float4 wa = *reinterpret_cast<const float4*>(wp);
        float4 wb = *reinterpret_cast<const float4*>(wp + 4);
        short8 hb;
        hb[0] = (short)f2b(wa.x); hb[1] = (short)f2b(wa.y); hb[2] = (short)f2b(wa.z); hb[3] = (short)f2b(wa.w);
        hb[4] = (short)f2b(wb.x); hb[5] = (short)f2b(wb.y); hb[6] = (short)f2b(wb.z); hb[7] = (short)f2b(wb.w);
        bfr[j] = hb;
      }
#pragma unroll
      for (int m = 0; m < 2; ++m)
#pragma unroll
        for (int j = 0; j < 2; ++j)
          acc[m][j] = __builtin_amdgcn_mfma_f32_16x16x32_bf16(af[m], bfr[j], acc[m][j], 0, 0, 0);
    }
    __syncthreads();
  }
#pragma unroll
  for (int m = 0; m < 2; ++m)
#pragma unroll
    for (int j = 0; j < 2; ++j)
#pragma unroll
      for (int r = 0; r < 4; ++r)
        atomicAdd(out + (size_t)(m * 16 + l4 * 4 + r) * 1024 + (n0 + wv * 32 + j * 16 + l15),
                  acc[m][j][r]);
}

// ---------------------------------------------------------------------------
// convert_att2 v6: Wf->bf16 (2 MB) + att2pre skinny gemm at K=256 slots.
//   [0,128)    Wf convert
//   [128,160)  att2pre: bid2=bid-128, nt=bid2&7, ks=bid2>>3 (4 K-slots x 256)
// More blocks -> att2pre's latency-bound chain halves; rides under the
// 128 convert blocks (160 total < 256 CUs, one dispatch wave).
// ---------------------------------------------------------------------------
__global__ __launch_bounds__(256) void convert_att2(
    const float* __restrict__ wf, unsigned short* __restrict__ wfb,
    const float* __restrict__ Wd, const float* __restrict__ dh,
    float* __restrict__ att2)
{
  const int bid = blockIdx.x;
  if (bid < 128) {
    const int base = bid * 1024;
#pragma unroll
    for (int j = 0; j < 4; ++j) {
      int g = base + j * 256 + (int)threadIdx.x;
      const float* s = wf + (size_t)g * 8;
      float4 a = *reinterpret_cast<const float4*>(s);
      float4 b = *reinterpret_cast<const float4*>(s + 4);
      short8 o;
      o[0] = (short)f2b(a.x); o[1] = (short)f2b(a.y); o[2] = (short)f2b(a.z); o[3] = (short)f2b(a.w);
      o[4] = (short)f2b(b.x); o[5] = (short)f2b(b.y); o[6] = (short)f2b(b.z); o[7] = (short)f2b(b.w);
      *reinterpret_cast<short8*>(wfb + (size_t)g * 8) = o;
    }
  } else {
    int bid2 = bid - 128;
    int nt = bid2 & 7, ks = bid2 >> 3;          // ks in [0,4)
    skinny_gemm(Wd, 1024, dh, dh, dh, ks * 256, ks * 256 + 256, nt * 128, att2);
  }
}

// ---------------------------------------------------------------------------
// gate_gemm v6: K-slots split 512 -> 256 for CU coverage (96 -> 192 blocks,
// latency-bound chain per block halves). Slot map (dim3(8,24)):
//   slot  0-11: Wg, kbeg = slot*256          -> ztp
//   slot 12-15: Ws, kbeg = (slot-12)*256     -> scp
//   slot 16-23: Wt, kbeg = (slot-16)*256     -> tcp
// atomicAdd accumulation -> order-independent, numerics unchanged in kind.
// ---------------------------------------------------------------------------
__global__ __launch_bounds__(256) void gate_gemm(
    const float* __restrict__ Wg, const float* __restrict__ Ws_,
    const float* __restrict__ Wt, const float* __restrict__ word,
    const float* __restrict__ dh, const float* __restrict__ ctx,
    float* __restrict__ ztp, float* __restrict__ scp, float* __restrict__ tcp)
{
  const int nt = blockIdx.x, slot = blockIdx.y;
  if (slot < 12)
    skinny_gemm(Wg, 3072, word, dh, ctx, slot * 256, slot * 256 + 256, nt * 128, ztp);
  else if (slot < 16)
    skinny_gemm(Ws_, 1024, ctx, ctx, ctx, (slot - 12) * 256, (slot - 12) * 256 + 256, nt * 128, scp);
  else
    skinny_gemm(Wt, 2048, word, dh, dh, (slot - 16) * 256, (slot - 16) * 256 + 256, nt * 128, tcp);
}

// ---------------------------------------------------------------------------
// att_gemm3 v5 (best-measured: 103.4-105.0 us, MfmaUtil ~27, VGPR 128):
// fused A-conversion with CROSS-BARRIER register staging. UNCHANGED — the
// band floor of this structure; 4 structural variants all regressed.
// Flights issued late in tile t hold A-tile (t+2)'s f32 data; converted +
// ds_written at the TOP of tile t+1 into slot (t+2)&1. Every vmem wait has
// >= 1 tile of cover. 128 VGPR + 128 acc = 256 unified regs = exactly
// 2 waves/SIMD; 128 KB LDS = 1 block/CU (measured cliffs both).
// ---------------------------------------------------------------------------
__global__ __launch_bounds__(512, 2) void att_gemm3(
    const float* __restrict__ cap, const unsigned short* __restrict__ wfb,
    const float* __restrict__ att2pre, const float* __restrict__ bfv,
    const float* __restrict__ bdv, const float* __restrict__ Wa,
    float* __restrict__ scores)
{
  __shared__ __align__(16) unsigned char lds[131072];   // 2 slots x (A 32K + B 32K)
  const int tid = threadIdx.x, lane = tid & 63, wv = tid >> 6;
  // bijective XCD chunking: nwg=512, 8 XCDs, 64 jobs/XCD
  const int j = ((int)blockIdx.x & 7) * 64 + ((int)blockIdx.x >> 3);
  const int mt = j >> 2, nt = j & 3;            // 128 m-tiles x 4 n-tiles
  const int m0 = mt << 8, n0 = nt << 8;
  const int bb = m0 >> 10;                      // batch (256 | 1024)
  const int wm = wv >> 2, wn = wv & 3;          // 2M x 4N
  const int l15 = lane & 15, l4 = lane >> 4;
  const int r8 = lane >> 3, c8 = lane & 7;
  const unsigned swb = (unsigned)((l15 & 7) << 4);

  // A staging source: f32, inverse-swizzled column (bf16 byte off / 2).
  const float* capA = cap + (size_t)(m0 + wv * 32 + r8) * 1024 +
                      ((unsigned)((c8 * 16) ^ (r8 << 4)) >> 1);
  // B stage source (bf16 wfb, DMA path)
  const unsigned char* bSrc = (const unsigned char*)wfb +
      (size_t)(n0 + wv * 32 + r8) * 2048 + ((c8 * 16) ^ (r8 << 4));
  const unsigned ldsBase = (unsigned)(size_t)(&lds[0]);

  f32x4 acc[8][4];
#pragma unroll
  for (int mf = 0; mf < 8; ++mf)
#pragma unroll
    for (int nf = 0; nf < 4; ++nf) acc[mf][nf] = (f32x4){0.f, 0.f, 0.f, 0.f};

#define STAGE_B(t) do { \
    const int sl__ = (t) & 1; \
    unsigned char* db__ = lds + sl__ * 65536 + 32768 + wv * 4096; \
    const unsigned char* gb__ = bSrc + (t) * 128; \
    GLOAD_LDS16(gb__,          db__); \
    GLOAD_LDS16(gb__ + 16384,  db__ + 1024); \
    GLOAD_LDS16(gb__ + 32768,  db__ + 2048); \
    GLOAD_LDS16(gb__ + 49152,  db__ + 3072); \
  } while (0)

// load one j-chunk pair (rows j0*8.. and (j0+1)*8..) of tile tt into 4 float4
#define FLIGHT(fA0, fA1, fB0, fB1, j0, tt) do { \
    const float* p0__ = capA + (size_t)(j0) * 8192 + (tt) * 64; \
    const float* p1__ = p0__ + 8192; \
    fA0 = *reinterpret_cast<const float4*>(p0__); \
    fA1 = *reinterpret_cast<const float4*>(p0__ + 4); \
    fB0 = *reinterpret_cast<const float4*>(p1__); \
    fB1 = *reinterpret_cast<const float4*>(p1__ + 4); \
  } while (0)

// convert 8 floats -> 16B bf16, store to LDS (linear lane*16: conflict-free)
#define PACK_WRITE(fA, fB, wp) do { \
    short8 o__; \
    o__[0] = (short)f2b(fA.x); o__[1] = (short)f2b(fA.y); \
    o__[2] = (short)f2b(fA.z); o__[3] = (short)f2b(fA.w); \
    o__[4] = (short)f2b(fB.x); o__[5] = (short)f2b(fB.y); \
    o__[6] = (short)f2b(fB.z); o__[7] = (short)f2b(fB.w); \
    *reinterpret_cast<short8*>(wp) = o__; \
  } while (0)

#define DSREAD(dst, addr) \
  asm volatile("ds_read_b128 %0, %1" : "=v"(dst) : "v"(addr))

// read one A quarter (32 rows): 4 x ds_read_b128 into dst[0..3]
#define READ_AQ(dst, q) do { \
_Pragma("unroll") \
    for (int mf2 = 0; mf2 < 2; ++mf2) \
_Pragma("unroll") \
      for (int ks = 0; ks < 2; ++ks) { \
        unsigned r__ = (unsigned)(wm * 128 + (q) * 32 + mf2 * 16 + l15); \
        DSREAD(dst[mf2 * 2 + ks], sA + r__ * 128 + (((unsigned)(ks * 64 + l4 * 16)) ^ swb)); \
      } \
  } while (0)

// read one B column-half (32 cols): 4 x ds_read_b128 into Breg[ch*4 ..]
#define READ_B(ch) do { \
_Pragma("unroll") \
    for (int nf = 0; nf < 2; ++nf) \
_Pragma("unroll") \
      for (int ks = 0; ks < 2; ++ks) { \
        unsigned c__ = (unsigned)(wn * 64 + (ch) * 32 + nf * 16 + l15); \
        DSREAD(Breg[(ch) * 4 + nf * 2 + ks], sB + c__ * 128 + (((unsigned)(ks * 64 + l4 * 16)) ^ swb)); \
      } \
  } while (0)

// 8 MFMAs: quarter q (rows q*32..+31) x column-half ch (cols ch*32..+31)
#define MFMA8(q, ch, Aq) do { \
    __builtin_amdgcn_s_setprio(1); \
_Pragma("unroll") \
    for (int mf2 = 0; mf2 < 2; ++mf2) \
_Pragma("unroll") \
      for (int nf = 0; nf < 2; ++nf) \
_Pragma("unroll") \
        for (int ks = 0; ks < 2; ++ks) \
          acc[(q) * 2 + mf2][(ch) * 2 + nf] = __builtin_amdgcn_mfma_f32_16x16x32_bf16( \
              Aq[mf2 * 2 + ks], Breg[(ch) * 4 + nf * 2 + ks], acc[(q) * 2 + mf2][(ch) * 2 + nf], 0, 0, 0); \
    __builtin_amdgcn_s_setprio(0); \
  } while (0)

#define WAIT_LGKM(n) do { \
    asm volatile("s_waitcnt lgkmcnt(" #n ")" ::: "memory"); \
    __builtin_amdgcn_sched_barrier(0); \
  } while (0)

  short8 Aq0[4], Aq1[4], Breg[8];
  float4 g0a, g0b, g1a, g1b;   // flight 1 (j-chunks 0,1)
  float4 g2a, g2b, g3a, g3b;   // flight 2 (j-chunks 2,3)

  // prologue: stage B(0) DMA + A(0) flights; drain; pack A(0) -> slot 0;
  // issue A(1) flights (held in regs, packed at top of t=0); join.
  STAGE_B(0);
  FLIGHT(g0a, g0b, g1a, g1b, 0, 0);
  FLIGHT(g2a, g2b, g3a, g3b, 2, 0);
  asm volatile("s_waitcnt vmcnt(0)" ::: "memory");
  {
    unsigned char* wp = lds + wv * 4096 + lane * 16;   // A slot 0
    PACK_WRITE(g0a, g0b, wp);
    PACK_WRITE(g1a, g1b, wp + 1024);
    PACK_WRITE(g2a, g2b, wp + 2048);
    PACK_WRITE(g3a, g3b, wp + 3072);
  }
  FLIGHT(g0a, g0b, g1a, g1b, 0, 1);
  FLIGHT(g2a, g2b, g3a, g3b, 2, 1);
  WAIT_LGKM(0);
  asm volatile("s_barrier" ::: "memory");

  for (int t = 0; t < 16; ++t) {
    const unsigned sA = ldsBase + (unsigned)((t & 1) * 65536);
    const unsigned sB = sA + 32768u;

    // (1) pack A(t+1) from flights issued in tile t-1 (full-tile cover)
    if (t < 15) {
      asm volatile("s_waitcnt vmcnt(0)" ::: "memory");
      __builtin_amdgcn_sched_barrier(0);
      unsigned char* wp = lds + ((t + 1) & 1) * 65536 + wv * 4096 + lane * 16;
      PACK_WRITE(g0a, g0b, wp);
      PACK_WRITE(g1a, g1b, wp + 1024);
      PACK_WRITE(g2a, g2b, wp + 2048);
      PACK_WRITE(g3a, g3b, wp + 3072);
    }
    // (2) stage B(t+1) via DMA (drained at end-of-tile wait)
    if (t < 15) STAGE_B(t + 1);

    // (3) read bursts for tile t (ds queue: [4 writes] + 16 reads)
    READ_AQ(Aq0, 0);
    READ_B(0);
    READ_B(1);
    READ_AQ(Aq1, 1);

    // (4) quarter-pipelined MFMA schedule (R2-proven)
    WAIT_LGKM(8);                       // writes + AQ0 + B(ch0) done
    MFMA8(0, 0, Aq0);
    WAIT_LGKM(4);                       // + B(ch1) done
    MFMA8(0, 1, Aq0);
    WAIT_LGKM(0);                       // + AQ1 done
    READ_AQ(Aq0, 2);                    // prefetch q2 (reuse Aq0)
    MFMA8(1, 0, Aq1);
    MFMA8(1, 1, Aq1);
    READ_AQ(Aq1, 3);                    // prefetch q3
    WAIT_LGKM(4);                       // AQ2 done (AQ3 in flight)
    MFMA8(2, 0, Aq0);
    MFMA8(2, 1, Aq0);
    // (5) flights for A(t+2): issued here, packed at top of t+1
    if (t < 14) FLIGHT(g0a, g0b, g1a, g1b, 0, t + 2);
    WAIT_LGKM(0);                       // AQ3 done
    MFMA8(3, 0, Aq1);
    MFMA8(3, 1, Aq1);
    if (t < 14) FLIGHT(g2a, g2b, g3a, g3b, 2, t + 2);

    // (6) end: drain only B-DMA (keep flights in flight), join
    if (t < 15) {
      if (t < 14) {
        asm volatile("s_waitcnt vmcnt(8)" ::: "memory");  // leave 8 flights
      } else {
        asm volatile("s_waitcnt vmcnt(0)" ::: "memory");  // only B DMA left
      }
      asm volatile("s_barrier" ::: "memory");
    }
  }

  // epilogue: s[m] = sum_n tanh(acc + colb[n]) * Wa[n], reduce over l15
  float colb[4], wav[4];
#pragma unroll
  for (int nf = 0; nf < 4; ++nf) {
    int cg = n0 + wn * 64 + nf * 16 + l15;
    colb[nf] = att2pre[bb * 1024 + cg] + bfv[cg] + bdv[cg];
    wav[nf]  = Wa[cg];
  }
#pragma unroll
  for (int mf = 0; mf < 8; ++mf) {
#pragma unroll
    for (int r = 0; r < 4; ++r) {
      float s = tanh_fast(acc[mf][0][r] + colb[0]) * wav[0]
              + tanh_fast(acc[mf][1][r] + colb[1]) * wav[1]
              + tanh_fast(acc[mf][2][r] + colb[2]) * wav[2]
              + tanh_fast(acc[mf][3][r] + colb[3]) * wav[3];
      s += __shfl_xor(s, 1);
      s += __shfl_xor(s, 2);
      s += __shfl_xor(s, 4);
      s += __shfl_xor(s, 8);
      if (l15 == 0)
        atomicAdd(scores + (m0 + wm * 128 + mf * 16 + l4 * 4 + r), s);
    }
  }
#undef STAGE_B
#undef FLIGHT
#undef PACK_WRITE
#undef DSREAD
#undef READ_AQ
#undef READ_B
#undef MFMA8
#undef WAIT_LGKM
}

// ---------------------------------------------------------------------------
__global__ __launch_bounds__(256) void softmax_k(
    const float* __restrict__ scores, const int* __restrict__ mask,
    float* __restrict__ alpha)
{
  const int b = blockIdx.x, tid = threadIdx.x;
  __shared__ float red[8];
  float s[4];
  float mx = -3.0e38f;
#pragma unroll
  for (int i = 0; i < 4; ++i) {
    int l = tid + i * 256;
    float v = scores[b * 1024 + l];
    v = (mask[b * 1024 + l] == 0) ? -1.0e10f : v;
    s[i] = v;
    mx = fmaxf(mx, v);
  }
  for (int off = 1; off < 64; off <<= 1) mx = fmaxf(mx, __shfl_xor(mx, off));
  int wv = tid >> 6;
  if ((tid & 63) == 0) red[wv] = mx;
  __syncthreads();
  mx = fmaxf(fmaxf(red[0], red[1]), fmaxf(red[2], red[3]));
  float sum = 0.f;
#pragma unroll
  for (int i = 0; i < 4; ++i) {
    s[i] = exp2f_fast((s[i] - mx) * LOG2E);
    sum += s[i];
  }
  for (int off = 1; off < 64; off <<= 1) sum += __shfl_xor(sum, off);
  if ((tid & 63) == 0) red[4 + wv] = sum;
  __syncthreads();
  sum = red[4] + red[5] + red[6] + red[7];
  float inv = 1.0f / sum;
#pragma unroll
  for (int i = 0; i < 4; ++i) alpha[b * 1024 + tid + i * 256] = s[i] * inv;
}

// ---------------------------------------------------------------------------
// ctx_kb: reads cap f32 directly (capb eliminated)
// ---------------------------------------------------------------------------
__global__ __launch_bounds__(256) void ctx_kb(
    const float* __restrict__ cap, const float* __restrict__ alpha,
    float* __restrict__ ctx)
{
  const int b = blockIdx.y, lc = blockIdx.x;
  const int dc = threadIdx.x & 127, loff = threadIdx.x >> 7;
  float acc[8] = {0.f, 0.f, 0.f, 0.f, 0.f, 0.f, 0.f, 0.f};
  for (int l = lc * 128 + loff; l < lc * 128 + 128; l += 2) {
    float av = alpha[b * 1024 + l];
    if (av != 0.f) {
      const float* p = cap + (((size_t)(b * 1024 + l)) << 10) + dc * 8;
      float4 v0 = *reinterpret_cast<const float4*>(p);
      float4 v1 = *reinterpret_cast<const float4*>(p + 4);
      acc[0] += av * v0.x; acc[1] += av * v0.y;
      acc[2] += av * v0.z; acc[3] += av * v0.w;
      acc[4] += av * v1.x; acc[5] += av * v1.y;
      acc[6] += av * v1.z; acc[7] += av * v1.w;
    }
  }
#pragma unroll
  for (int j = 0; j < 8; ++j) atomicAdd(ctx + b * 1024 + dc * 8 + j, acc[j]);
}

// ---------------------------------------------------------------------------
__global__ __launch_bounds__(256) void final_k(
    const float* __restrict__ ztp, const float* __restrict__ scp,
    const float* __restrict__ tcp, const float* __restrict__ bg,
    const float* __restrict__ bs, const float* __restrict__ bt,
    float* __restrict__ out)
{
  const int idx = blockIdx.x * 256 + threadIdx.x;
  const int d = idx & 1023;
  float z  = rcp_fast(1.0f + exp2f_fast(-(ztp[idx] + bg[d]) * LOG2E));
  float sc = tanh_fast(scp[idx] + bs[d]);
  float tc = tanh_fast(tcp[idx] + bt[d]);
  out[idx] = z * sc + (1.0f - z) * tc;
}

extern "C" void kernel_launch(void* const* d_in, const int* in_sizes, int n_in,
                              void* d_out, int out_size, void* d_ws, size_t ws_size,
                              hipStream_t stream) {
  const float* cap  = (const float*)d_in[0];
  const float* dh   = (const float*)d_in[1];
  const float* word = (const float*)d_in[2];
  const int*   mask = (const int*)d_in[3];
  const float* Wf   = (const float*)d_in[4];
  const float* bf   = (const float*)d_in[5];
  const float* Wd   = (const float*)d_in[6];
  const float* bd   = (const float*)d_in[7];
  const float* Wa   = (const float*)d_in[8];
  // d_in[9] = ba: softmax-invariant, dropped.
  const float* Wg   = (const float*)d_in[10];
  const float* bg   = (const float*)d_in[11];
  const float* Ws   = (const float*)d_in[12];
  const float* bs   = (const float*)d_in[13];
  const float* Wt   = (const float*)d_in[14];
  const float* bt   = (const float*)d_in[15];

  float* out_g = (float*)d_out;            // (32,1024) gated_context
  float* alpha = (float*)d_out + 32768;    // (32,1024) alpha

  float* att2pre = (float*)d_ws;           // 6 x 32768 f32 (zeroed)
  float* scores  = att2pre + 32768;
  float* ctx     = scores + 32768;
  float* ztp     = ctx + 32768;
  float* scp     = ztp + 32768;
  float* tcp     = scp + 32768;
  unsigned short* wfb = (unsigned short*)((char*)d_ws + 786432);  // 2 MB

  hipMemsetAsync(d_ws, 0, 6 * 32768 * sizeof(float), stream);

  convert_att2<<<160, 256, 0, stream>>>(Wf, wfb, Wd, dh, att2pre);
  att_gemm3<<<512, 512, 0, stream>>>(cap, wfb, att2pre, bf, bd, Wa, scores);
  softmax_k<<<32, 256, 0, stream>>>(scores, mask, alpha);
  ctx_kb<<<dim3(8, 32), 256, 0, stream>>>(cap, alpha, ctx);
  gate_gemm<<<dim3(8, 24), 256, 0, stream>>>(Wg, Ws, Wt, word, dh, ctx, ztp, scp, tcp);
  final_k<<<128, 256, 0, stream>>>(ztp, scp, tcp, bg, bs, bt, out_g);
}

// Round 12
// 140.496 us; speedup vs baseline: 1.1926x; 1.0252x over previous
//
#include <hip/hip_runtime.h>
#include <hip/hip_bf16.h>
#include <cstdint>
#include <cstddef>

#define LOG2E 1.4426950408889634f

typedef __attribute__((ext_vector_type(8))) short short8;
typedef __attribute__((ext_vector_type(4))) float f32x4;

__device__ __forceinline__ float exp2f_fast(float x) { return __builtin_amdgcn_exp2f(x); }
__device__ __forceinline__ float rcp_fast(float x)   { return __builtin_amdgcn_rcpf(x); }
__device__ __forceinline__ float tanh_fast(float x) {
  float e = exp2f_fast(x * (2.0f * LOG2E));
  return 1.0f - 2.0f * rcp_fast(e + 1.0f);
}
__device__ __forceinline__ unsigned short f2b(float f) {  // f32 -> bf16 RNE
  union { float f; unsigned int u; } v; v.f = f;
  return (unsigned short)((v.u + 0x7FFFu + ((v.u >> 16) & 1u)) >> 16);
}
__device__ __forceinline__ float b2f(short h) {
  union { unsigned u; float f; } w; w.u = ((unsigned)(unsigned short)h) << 16;
  return w.f;
}

#define GLOAD_LDS16(g, l) \
  __builtin_amdgcn_global_load_lds((const __attribute__((address_space(1))) unsigned int*)(g), \
                                   (__attribute__((address_space(3))) unsigned int*)(l), 16, 0, 0)

// ---------------------------------------------------------------------------
// Skinny MFMA GEMM helper (M=32): out[b, n0..n0+127] += X @ W^T
// Works for any [kbeg,kend) aligned to 64 (x-operand chosen by global k).
// ---------------------------------------------------------------------------
__device__ __forceinline__ void skinny_gemm(
    const float* __restrict__ W, int Kfull,
    const float* __restrict__ x0, const float* __restrict__ x1,
    const float* __restrict__ x2,
    int kbeg, int kend, int n0, float* __restrict__ out)
{
  __shared__ unsigned char sX[4096];   // 32 rows x 64 k bf16, XOR-swizzled
  const int tid = threadIdx.x, lane = tid & 63, wv = tid >> 6;
  const int l15 = lane & 15, l4 = lane >> 4;
  f32x4 acc[2][2];
#pragma unroll
  for (int m = 0; m < 2; ++m)
#pragma unroll
    for (int j = 0; j < 2; ++j) acc[m][j] = (f32x4){0.f, 0.f, 0.f, 0.f};

  const int srow = tid >> 3, skc = (tid & 7) * 8;
  const int sbyte = srow * 128 + ((skc * 2) ^ ((srow & 7) << 4));

  for (int k0 = kbeg; k0 < kend; k0 += 64) {
    const float* xs = (k0 < 1024) ? x0 : (k0 < 2048) ? x1 : x2;
    const float* xp = xs + srow * 1024 + (k0 & 1023) + skc;
    float4 a = *reinterpret_cast<const float4*>(xp);
    float4 b = *reinterpret_cast<const float4*>(xp + 4);
    short8 h;
    h[0] = (short)f2b(a.x); h[1] = (short)f2b(a.y); h[2] = (short)f2b(a.z); h[3] = (short)f2b(a.w);
    h[4] = (short)f2b(b.x); h[5] = (short)f2b(b.y); h[6] = (short)f2b(b.z); h[7] = (short)f2b(b.w);
    *reinterpret_cast<short8*>(sX + sbyte) = h;
    __syncthreads();
#pragma unroll
    for (int ks = 0; ks < 2; ++ks) {
      short8 af[2], bfr[2];
#pragma unroll
      for (int m = 0; m < 2; ++m) {
        int r = m * 16 + l15;
        af[m] = *reinterpret_cast<const short8*>(
            sX + r * 128 + (((ks * 64) + l4 * 16) ^ ((r & 7) << 4)));
      }
#pragma unroll
      for (int j = 0; j < 2; ++j) {
        int n = n0 + wv * 32 + j * 16 + l15;
        const float* wp = W + (size_t)n * Kfull + k0 + ks * 32 + l4 * 8;
        float4 wa = *reinterpret_cast<const float4*>(wp);
        float4 wb = *reinterpret_cast<const float4*>(wp + 4);
        short8 hb;
        hb[0] = (short)f2b(wa.x); hb[1] = (short)f2b(wa.y); hb[2] = (short)f2b(wa.z); hb[3] = (short)f2b(wa.w);
        hb[4] = (short)f2b(wb.x); hb[5] = (short)f2b(wb.y); hb[6] = (short)f2b(wb.z); hb[7] = (short)f2b(wb.w);
        bfr[j] = hb;
      }
#pragma unroll
      for (int m = 0; m < 2; ++m)
#pragma unroll
        for (int j = 0; j < 2; ++j)
          acc[m][j] = __builtin_amdgcn_mfma_f32_16x16x32_bf16(af[m], bfr[j], acc[m][j], 0, 0, 0);
    }
    __syncthreads();
  }
#pragma unroll
  for (int m = 0; m < 2; ++m)
#pragma unroll
    for (int j = 0; j < 2; ++j)
#pragma unroll
      for (int r = 0; r < 4; ++r)
        atomicAdd(out + (size_t)(m * 16 + l4 * 4 + r) * 1024 + (n0 + wv * 32 + j * 16 + l15),
                  acc[m][j][r]);
}

// ---------------------------------------------------------------------------
// convert_att2 v7: Wf->bf16 (2 MB) + att2pre skinny gemm at K=128 slots.
//   [0,128)    Wf convert
//   [128,192)  att2pre: bid2=bid-128, nt=bid2&7, ks=bid2>>3 (8 K-slots x 128)
// ---------------------------------------------------------------------------
__global__ __launch_bounds__(256) void convert_att2(
    const float* __restrict__ wf, unsigned short* __restrict__ wfb,
    const float* __restrict__ Wd, const float* __restrict__ dh,
    float* __restrict__ att2)
{
  const int bid = blockIdx.x;
  if (bid < 128) {
    const int base = bid * 1024;
#pragma unroll
    for (int j = 0; j < 4; ++j) {
      int g = base + j * 256 + (int)threadIdx.x;
      const float* s = wf + (size_t)g * 8;
      float4 a = *reinterpret_cast<const float4*>(s);
      float4 b = *reinterpret_cast<const float4*>(s + 4);
      short8 o;
      o[0] = (short)f2b(a.x); o[1] = (short)f2b(a.y); o[2] = (short)f2b(a.z); o[3] = (short)f2b(a.w);
      o[4] = (short)f2b(b.x); o[5] = (short)f2b(b.y); o[6] = (short)f2b(b.z); o[7] = (short)f2b(b.w);
      *reinterpret_cast<short8*>(wfb + (size_t)g * 8) = o;
    }
  } else {
    int bid2 = bid - 128;
    int nt = bid2 & 7, ks = bid2 >> 3;          // ks in [0,8)
    skinny_gemm(Wd, 1024, dh, dh, dh, ks * 128, ks * 128 + 128, nt * 128, att2);
  }
}

// ---------------------------------------------------------------------------
// gate_gemm v7: K-slots 256 -> 128 (192 -> 384 blocks). Slot map (dim3(8,48)):
//   slot  0-23: Wg, kbeg = slot*128          -> ztp
//   slot 24-31: Ws, kbeg = (slot-24)*128     -> scp
//   slot 32-47: Wt, kbeg = (slot-32)*128     -> tcp
// atomicAdd accumulation -> order-independent.
// ---------------------------------------------------------------------------
__global__ __launch_bounds__(256) void gate_gemm(
    const float* __restrict__ Wg, const float* __restrict__ Ws_,
    const float* __restrict__ Wt, const float* __restrict__ word,
    const float* __restrict__ dh, const float* __restrict__ ctx,
    float* __restrict__ ztp, float* __restrict__ scp, float* __restrict__ tcp)
{
  const int nt = blockIdx.x, slot = blockIdx.y;
  if (slot < 24)
    skinny_gemm(Wg, 3072, word, dh, ctx, slot * 128, slot * 128 + 128, nt * 128, ztp);
  else if (slot < 32)
    skinny_gemm(Ws_, 1024, ctx, ctx, ctx, (slot - 24) * 128, (slot - 24) * 128 + 128, nt * 128, scp);
  else
    skinny_gemm(Wt, 2048, word, dh, dh, (slot - 32) * 128, (slot - 32) * 128 + 128, nt * 128, tcp);
}

// ---------------------------------------------------------------------------
// att_gemm3 v5 (best-measured: 103.4-106 us, MfmaUtil ~27, VGPR 128):
// UNCHANGED — the band floor of this structure; 4 structural variants all
// regressed. Fused A-conversion with CROSS-BARRIER register staging.
// 128 VGPR + 128 acc = 256 unified regs = exactly 2 waves/SIMD; 128 KB LDS
// = 1 block/CU (measured cliffs both).
// ---------------------------------------------------------------------------
__global__ __launch_bounds__(512, 2) void att_gemm3(
    const float* __restrict__ cap, const unsigned short* __restrict__ wfb,
    const float* __restrict__ att2pre, const float* __restrict__ bfv,
    const float* __restrict__ bdv, const float* __restrict__ Wa,
    float* __restrict__ scores)
{
  __shared__ __align__(16) unsigned char lds[131072];   // 2 slots x (A 32K + B 32K)
  const int tid = threadIdx.x, lane = tid & 63, wv = tid >> 6;
  // bijective XCD chunking: nwg=512, 8 XCDs, 64 jobs/XCD
  const int j = ((int)blockIdx.x & 7) * 64 + ((int)blockIdx.x >> 3);
  const int mt = j >> 2, nt = j & 3;            // 128 m-tiles x 4 n-tiles
  const int m0 = mt << 8, n0 = nt << 8;
  const int bb = m0 >> 10;                      // batch (256 | 1024)
  const int wm = wv >> 2, wn = wv & 3;          // 2M x 4N
  const int l15 = lane & 15, l4 = lane >> 4;
  const int r8 = lane >> 3, c8 = lane & 7;
  const unsigned swb = (unsigned)((l15 & 7) << 4);

  // A staging source: f32, inverse-swizzled column (bf16 byte off / 2).
  const float* capA = cap + (size_t)(m0 + wv * 32 + r8) * 1024 +
                      ((unsigned)((c8 * 16) ^ (r8 << 4)) >> 1);
  // B stage source (bf16 wfb, DMA path)
  const unsigned char* bSrc = (const unsigned char*)wfb +
      (size_t)(n0 + wv * 32 + r8) * 2048 + ((c8 * 16) ^ (r8 << 4));
  const unsigned ldsBase = (unsigned)(size_t)(&lds[0]);

  f32x4 acc[8][4];
#pragma unroll
  for (int mf = 0; mf < 8; ++mf)
#pragma unroll
    for (int nf = 0; nf < 4; ++nf) acc[mf][nf] = (f32x4){0.f, 0.f, 0.f, 0.f};

#define STAGE_B(t) do { \
    const int sl__ = (t) & 1; \
    unsigned char* db__ = lds + sl__ * 65536 + 32768 + wv * 4096; \
    const unsigned char* gb__ = bSrc + (t) * 128; \
    GLOAD_LDS16(gb__,          db__); \
    GLOAD_LDS16(gb__ + 16384,  db__ + 1024); \
    GLOAD_LDS16(gb__ + 32768,  db__ + 2048); \
    GLOAD_LDS16(gb__ + 49152,  db__ + 3072); \
  } while (0)

// load one j-chunk pair (rows j0*8.. and (j0+1)*8..) of tile tt into 4 float4
#define FLIGHT(fA0, fA1, fB0, fB1, j0, tt) do { \
    const float* p0__ = capA + (size_t)(j0) * 8192 + (tt) * 64; \
    const float* p1__ = p0__ + 8192; \
    fA0 = *reinterpret_cast<const float4*>(p0__); \
    fA1 = *reinterpret_cast<const float4*>(p0__ + 4); \
    fB0 = *reinterpret_cast<const float4*>(p1__); \
    fB1 = *reinterpret_cast<const float4*>(p1__ + 4); \
  } while (0)

// convert 8 floats -> 16B bf16, store to LDS (linear lane*16: conflict-free)
#define PACK_WRITE(fA, fB, wp) do { \
    short8 o__; \
    o__[0] = (short)f2b(fA.x); o__[1] = (short)f2b(fA.y); \
    o__[2] = (short)f2b(fA.z); o__[3] = (short)f2b(fA.w); \
    o__[4] = (short)f2b(fB.x); o__[5] = (short)f2b(fB.y); \
    o__[6] = (short)f2b(fB.z); o__[7] = (short)f2b(fB.w); \
    *reinterpret_cast<short8*>(wp) = o__; \
  } while (0)

#define DSREAD(dst, addr) \
  asm volatile("ds_read_b128 %0, %1" : "=v"(dst) : "v"(addr))

// read one A quarter (32 rows): 4 x ds_read_b128 into dst[0..3]
#define READ_AQ(dst, q) do { \
_Pragma("unroll") \
    for (int mf2 = 0; mf2 < 2; ++mf2) \
_Pragma("unroll") \
      for (int ks = 0; ks < 2; ++ks) { \
        unsigned r__ = (unsigned)(wm * 128 + (q) * 32 + mf2 * 16 + l15); \
        DSREAD(dst[mf2 * 2 + ks], sA + r__ * 128 + (((unsigned)(ks * 64 + l4 * 16)) ^ swb)); \
      } \
  } while (0)

// read one B column-half (32 cols): 4 x ds_read_b128 into Breg[ch*4 ..]
#define READ_B(ch) do { \
_Pragma("unroll") \
    for (int nf = 0; nf < 2; ++nf) \
_Pragma("unroll") \
      for (int ks = 0; ks < 2; ++ks) { \
        unsigned c__ = (unsigned)(wn * 64 + (ch) * 32 + nf * 16 + l15); \
        DSREAD(Breg[(ch) * 4 + nf * 2 + ks], sB + c__ * 128 + (((unsigned)(ks * 64 + l4 * 16)) ^ swb)); \
      } \
  } while (0)

// 8 MFMAs: quarter q (rows q*32..+31) x column-half ch (cols ch*32..+31)
#define MFMA8(q, ch, Aq) do { \
    __builtin_amdgcn_s_setprio(1); \
_Pragma("unroll") \
    for (int mf2 = 0; mf2 < 2; ++mf2) \
_Pragma("unroll") \
      for (int nf = 0; nf < 2; ++nf) \
_Pragma("unroll") \
        for (int ks = 0; ks < 2; ++ks) \
          acc[(q) * 2 + mf2][(ch) * 2 + nf] = __builtin_amdgcn_mfma_f32_16x16x32_bf16( \
              Aq[mf2 * 2 + ks], Breg[(ch) * 4 + nf * 2 + ks], acc[(q) * 2 + mf2][(ch) * 2 + nf], 0, 0, 0); \
    __builtin_amdgcn_s_setprio(0); \
  } while (0)

#define WAIT_LGKM(n) do { \
    asm volatile("s_waitcnt lgkmcnt(" #n ")" ::: "memory"); \
    __builtin_amdgcn_sched_barrier(0); \
  } while (0)

  short8 Aq0[4], Aq1[4], Breg[8];
  float4 g0a, g0b, g1a, g1b;   // flight 1 (j-chunks 0,1)
  float4 g2a, g2b, g3a, g3b;   // flight 2 (j-chunks 2,3)

  // prologue: stage B(0) DMA + A(0) flights; drain; pack A(0) -> slot 0;
  // issue A(1) flights (held in regs, packed at top of t=0); join.
  STAGE_B(0);
  FLIGHT(g0a, g0b, g1a, g1b, 0, 0);
  FLIGHT(g2a, g2b, g3a, g3b, 2, 0);
  asm volatile("s_waitcnt vmcnt(0)" ::: "memory");
  {
    unsigned char* wp = lds + wv * 4096 + lane * 16;   // A slot 0
    PACK_WRITE(g0a, g0b, wp);
    PACK_WRITE(g1a, g1b, wp + 1024);
    PACK_WRITE(g2a, g2b, wp + 2048);
    PACK_WRITE(g3a, g3b, wp + 3072);
  }
  FLIGHT(g0a, g0b, g1a, g1b, 0, 1);
  FLIGHT(g2a, g2b, g3a, g3b, 2, 1);
  WAIT_LGKM(0);
  asm volatile("s_barrier" ::: "memory");

  for (int t = 0; t < 16; ++t) {
    const unsigned sA = ldsBase + (unsigned)((t & 1) * 65536);
    const unsigned sB = sA + 32768u;

    // (1) pack A(t+1) from flights issued in tile t-1 (full-tile cover)
    if (t < 15) {
      asm volatile("s_waitcnt vmcnt(0)" ::: "memory");
      __builtin_amdgcn_sched_barrier(0);
      unsigned char* wp = lds + ((t + 1) & 1) * 65536 + wv * 4096 + lane * 16;
      PACK_WRITE(g0a, g0b, wp);
      PACK_WRITE(g1a, g1b, wp + 1024);
      PACK_WRITE(g2a, g2b, wp + 2048);
      PACK_WRITE(g3a, g3b, wp + 3072);
    }
    // (2) stage B(t+1) via DMA (drained at end-of-tile wait)
    if (t < 15) STAGE_B(t + 1);

    // (3) read bursts for tile t (ds queue: [4 writes] + 16 reads)
    READ_AQ(Aq0, 0);
    READ_B(0);
    READ_B(1);
    READ_AQ(Aq1, 1);

    // (4) quarter-pipelined MFMA schedule (R2-proven)
    WAIT_LGKM(8);                       // writes + AQ0 + B(ch0) done
    MFMA8(0, 0, Aq0);
    WAIT_LGKM(4);                       // + B(ch1) done
    MFMA8(0, 1, Aq0);
    WAIT_LGKM(0);                       // + AQ1 done
    READ_AQ(Aq0, 2);                    // prefetch q2 (reuse Aq0)
    MFMA8(1, 0, Aq1);
    MFMA8(1, 1, Aq1);
    READ_AQ(Aq1, 3);                    // prefetch q3
    WAIT_LGKM(4);                       // AQ2 done (AQ3 in flight)
    MFMA8(2, 0, Aq0);
    MFMA8(2, 1, Aq0);
    // (5) flights for A(t+2): issued here, packed at top of t+1
    if (t < 14) FLIGHT(g0a, g0b, g1a, g1b, 0, t + 2);
    WAIT_LGKM(0);                       // AQ3 done
    MFMA8(3, 0, Aq1);
    MFMA8(3, 1, Aq1);
    if (t < 14) FLIGHT(g2a, g2b, g3a, g3b, 2, t + 2);

    // (6) end: drain only B-DMA (keep flights in flight), join
    if (t < 15) {
      if (t < 14) {
        asm volatile("s_waitcnt vmcnt(8)" ::: "memory");  // leave 8 flights
      } else {
        asm volatile("s_waitcnt vmcnt(0)" ::: "memory");  // only B DMA left
      }
      asm volatile("s_barrier" ::: "memory");
    }
  }

  // epilogue: s[m] = sum_n tanh(acc + colb[n]) * Wa[n], reduce over l15
  float colb[4], wav[4];
#pragma unroll
  for (int nf = 0; nf < 4; ++nf) {
    int cg = n0 + wn * 64 + nf * 16 + l15;
    colb[nf] = att2pre[bb * 1024 + cg] + bfv[cg] + bdv[cg];
    wav[nf]  = Wa[cg];
  }
#pragma unroll
  for (int mf = 0; mf < 8; ++mf) {
#pragma unroll
    for (int r = 0; r < 4; ++r) {
      float s = tanh_fast(acc[mf][0][r] + colb[0]) * wav[0]
              + tanh_fast(acc[mf][1][r] + colb[1]) * wav[1]
              + tanh_fast(acc[mf][2][r] + colb[2]) * wav[2]
              + tanh_fast(acc[mf][3][r] + colb[3]) * wav[3];
      s += __shfl_xor(s, 1);
      s += __shfl_xor(s, 2);
      s += __shfl_xor(s, 4);
      s += __shfl_xor(s, 8);
      if (l15 == 0)
        atomicAdd(scores + (m0 + wm * 128 + mf * 16 + l4 * 4 + r), s);
    }
  }
#undef STAGE_B
#undef FLIGHT
#undef PACK_WRITE
#undef DSREAD
#undef READ_AQ
#undef READ_B
#undef MFMA8
#undef WAIT_LGKM
}

// ---------------------------------------------------------------------------
// sm_ctx_k: fused softmax + context. Grid dim3(16,32): lc = 64-wide l-chunk,
// b = batch. Each block redundantly computes its row's softmax stats
// (scores row = 4 KB, L2-hot; identical arithmetic per block -> alpha
// bitwise-identical to the old softmax_k), writes its disjoint alpha chunk,
// then accumulates ctx over its chunk (alpha==0 rows skipped, wave-uniform).
// Replaces softmax_k + ctx_kb: one fewer kernel/gap, 2x ctx parallelism.
// ---------------------------------------------------------------------------
__global__ __launch_bounds__(256) void sm_ctx_k(
    const float* __restrict__ scores, const int* __restrict__ mask,
    const float* __restrict__ cap, float* __restrict__ alpha,
    float* __restrict__ ctx)
{
  const int b = blockIdx.y, lc = blockIdx.x, tid = threadIdx.x;
  __shared__ float red[8];
  __shared__ float aChunk[64];
  float s[4];
  float mx = -3.0e38f;
#pragma unroll
  for (int i = 0; i < 4; ++i) {
    int l = tid + i * 256;
    float v = scores[b * 1024 + l];
    v = (mask[b * 1024 + l] == 0) ? -1.0e10f : v;
    s[i] = v;
    mx = fmaxf(mx, v);
  }
  for (int off = 1; off < 64; off <<= 1) mx = fmaxf(mx, __shfl_xor(mx, off));
  int wv = tid >> 6;
  if ((tid & 63) == 0) red[wv] = mx;
  __syncthreads();
  mx = fmaxf(fmaxf(red[0], red[1]), fmaxf(red[2], red[3]));
  float sum = 0.f;
#pragma unroll
  for (int i = 0; i < 4; ++i) {
    s[i] = exp2f_fast((s[i] - mx) * LOG2E);
    sum += s[i];
  }
  for (int off = 1; off < 64; off <<= 1) sum += __shfl_xor(sum, off);
  if ((tid & 63) == 0) red[4 + wv] = sum;
  __syncthreads();
  sum = red[4] + red[5] + red[6] + red[7];
  float inv = 1.0f / sum;

  // write this block's alpha chunk [lc*64, lc*64+64): thread t0+j holds
  // l = i0*256 + t0 + j = lc*64 + j  (chunks are 256-aligned in groups of 4)
  const int i0 = lc >> 2, t0 = (lc & 3) * 64;
  if ((unsigned)(tid - t0) < 64u) {
    float av = s[i0] * inv;
    alpha[b * 1024 + lc * 64 + (tid - t0)] = av;
    aChunk[tid - t0] = av;
  }
  __syncthreads();

  // ctx accumulation over this 64-l chunk
  const int dc = tid & 127, loff = tid >> 7;
  float acc[8] = {0.f, 0.f, 0.f, 0.f, 0.f, 0.f, 0.f, 0.f};
  for (int li = loff; li < 64; li += 2) {
    float av = aChunk[li];
    if (av != 0.f) {                     // wave-uniform (li uniform)
      const float* p = cap + (((size_t)(b * 1024 + lc * 64 + li)) << 10) + dc * 8;
      float4 v0 = *reinterpret_cast<const float4*>(p);
      float4 v1 = *reinterpret_cast<const float4*>(p + 4);
      acc[0] += av * v0.x; acc[1] += av * v0.y;
      acc[2] += av * v0.z; acc[3] += av * v0.w;
      acc[4] += av * v1.x; acc[5] += av * v1.y;
      acc[6] += av * v1.z; acc[7] += av * v1.w;
    }
  }
#pragma unroll
  for (int j = 0; j < 8; ++j) atomicAdd(ctx + b * 1024 + dc * 8 + j, acc[j]);
}

// ---------------------------------------------------------------------------
__global__ __launch_bounds__(256) void final_k(
    const float* __restrict__ ztp, const float* __restrict__ scp,
    const float* __restrict__ tcp, const float* __restrict__ bg,
    const float* __restrict__ bs, const float* __restrict__ bt,
    float* __restrict__ out)
{
  const int idx = blockIdx.x * 256 + threadIdx.x;
  const int d = idx & 1023;
  float z  = rcp_fast(1.0f + exp2f_fast(-(ztp[idx] + bg[d]) * LOG2E));
  float sc = tanh_fast(scp[idx] + bs[d]);
  float tc = tanh_fast(tcp[idx] + bt[d]);
  out[idx] = z * sc + (1.0f - z) * tc;
}

extern "C" void kernel_launch(void* const* d_in, const int* in_sizes, int n_in,
                              void* d_out, int out_size, void* d_ws, size_t ws_size,
                              hipStream_t stream) {
  const float* cap  = (const float*)d_in[0];
  const float* dh   = (const float*)d_in[1];
  const float* word = (const float*)d_in[2];
  const int*   mask = (const int*)d_in[3];
  const float* Wf   = (const float*)d_in[4];
  const float* bf   = (const float*)d_in[5];
  const float* Wd   = (const float*)d_in[6];
  const float* bd   = (const float*)d_in[7];
  const float* Wa   = (const float*)d_in[8];
  // d_in[9] = ba: softmax-invariant, dropped.
  const float* Wg   = (const float*)d_in[10];
  const float* bg   = (const float*)d_in[11];
  const float* Ws   = (const float*)d_in[12];
  const float* bs   = (const float*)d_in[13];
  const float* Wt   = (const float*)d_in[14];
  const float* bt   = (const float*)d_in[15];

  float* out_g = (float*)d_out;            // (32,1024) gated_context
  float* alpha = (float*)d_out + 32768;    // (32,1024) alpha

  float* att2pre = (float*)d_ws;           // 6 x 32768 f32 (zeroed)
  float* scores  = att2pre + 32768;
  float* ctx     = scores + 32768;
  float* ztp     = ctx + 32768;
  float* scp     = ztp + 32768;
  float* tcp     = scp + 32768;
  unsigned short* wfb = (unsigned short*)((char*)d_ws + 786432);  // 2 MB

  hipMemsetAsync(d_ws, 0, 6 * 32768 * sizeof(float), stream);

  convert_att2<<<192, 256, 0, stream>>>(Wf, wfb, Wd, dh, att2pre);
  att_gemm3<<<512, 512, 0, stream>>>(cap, wfb, att2pre, bf, bd, Wa, scores);
  sm_ctx_k<<<dim3(16, 32), 256, 0, stream>>>(scores, mask, cap, alpha, ctx);
  gate_gemm<<<dim3(8, 48), 256, 0, stream>>>(Wg, Ws, Wt, word, dh, ctx, ztp, scp, tcp);
  final_k<<<128, 256, 0, stream>>>(ztp, scp, tcp, bg, bs, bt, out_g);
}

// Round 13
// 139.987 us; speedup vs baseline: 1.1969x; 1.0036x over previous
//
#include <hip/hip_runtime.h>
#include <hip/hip_bf16.h>
#include <cstdint>
#include <cstddef>

#define LOG2E 1.4426950408889634f

typedef __attribute__((ext_vector_type(8))) short short8;
typedef __attribute__((ext_vector_type(4))) float f32x4;

__device__ __forceinline__ float exp2f_fast(float x) { return __builtin_amdgcn_exp2f(x); }
__device__ __forceinline__ float rcp_fast(float x)   { return __builtin_amdgcn_rcpf(x); }
__device__ __forceinline__ float tanh_fast(float x) {
  float e = exp2f_fast(x * (2.0f * LOG2E));
  return 1.0f - 2.0f * rcp_fast(e + 1.0f);
}
__device__ __forceinline__ unsigned short f2b(float f) {  // f32 -> bf16 RNE
  union { float f; unsigned int u; } v; v.f = f;
  return (unsigned short)((v.u + 0x7FFFu + ((v.u >> 16) & 1u)) >> 16);
}
__device__ __forceinline__ float b2f(short h) {
  union { unsigned u; float f; } w; w.u = ((unsigned)(unsigned short)h) << 16;
  return w.f;
}

#define GLOAD_LDS16(g, l) \
  __builtin_amdgcn_global_load_lds((const __attribute__((address_space(1))) unsigned int*)(g), \
                                   (__attribute__((address_space(3))) unsigned int*)(l), 16, 0, 0)

// ---------------------------------------------------------------------------
// Skinny MFMA GEMM helper (M=32): out[b, n0..n0+127] += X @ W^T
// Works for any [kbeg,kend) aligned to 64 (x-operand chosen by global k).
// ---------------------------------------------------------------------------
__device__ __forceinline__ void skinny_gemm(
    const float* __restrict__ W, int Kfull,
    const float* __restrict__ x0, const float* __restrict__ x1,
    const float* __restrict__ x2,
    int kbeg, int kend, int n0, float* __restrict__ out)
{
  __shared__ unsigned char sX[4096];   // 32 rows x 64 k bf16, XOR-swizzled
  const int tid = threadIdx.x, lane = tid & 63, wv = tid >> 6;
  const int l15 = lane & 15, l4 = lane >> 4;
  f32x4 acc[2][2];
#pragma unroll
  for (int m = 0; m < 2; ++m)
#pragma unroll
    for (int j = 0; j < 2; ++j) acc[m][j] = (f32x4){0.f, 0.f, 0.f, 0.f};

  const int srow = tid >> 3, skc = (tid & 7) * 8;
  const int sbyte = srow * 128 + ((skc * 2) ^ ((srow & 7) << 4));

  for (int k0 = kbeg; k0 < kend; k0 += 64) {
    const float* xs = (k0 < 1024) ? x0 : (k0 < 2048) ? x1 : x2;
    const float* xp = xs + srow * 1024 + (k0 & 1023) + skc;
    float4 a = *reinterpret_cast<const float4*>(xp);
    float4 b = *reinterpret_cast<const float4*>(xp + 4);
    short8 h;
    h[0] = (short)f2b(a.x); h[1] = (short)f2b(a.y); h[2] = (short)f2b(a.z); h[3] = (short)f2b(a.w);
    h[4] = (short)f2b(b.x); h[5] = (short)f2b(b.y); h[6] = (short)f2b(b.z); h[7] = (short)f2b(b.w);
    *reinterpret_cast<short8*>(sX + sbyte) = h;
    __syncthreads();
#pragma unroll
    for (int ks = 0; ks < 2; ++ks) {
      short8 af[2], bfr[2];
#pragma unroll
      for (int m = 0; m < 2; ++m) {
        int r = m * 16 + l15;
        af[m] = *reinterpret_cast<const short8*>(
            sX + r * 128 + (((ks * 64) + l4 * 16) ^ ((r & 7) << 4)));
      }
#pragma unroll
      for (int j = 0; j < 2; ++j) {
        int n = n0 + wv * 32 + j * 16 + l15;
        const float* wp = W + (size_t)n * Kfull + k0 + ks * 32 + l4 * 8;
        float4 wa = *reinterpret_cast<const float4*>(wp);
        float4 wb = *reinterpret_cast<const float4*>(wp + 4);
        short8 hb;
        hb[0] = (short)f2b(wa.x); hb[1] = (short)f2b(wa.y); hb[2] = (short)f2b(wa.z); hb[3] = (short)f2b(wa.w);
        hb[4] = (short)f2b(wb.x); hb[5] = (short)f2b(wb.y); hb[6] = (short)f2b(wb.z); hb[7] = (short)f2b(wb.w);
        bfr[j] = hb;
      }
#pragma unroll
      for (int m = 0; m < 2; ++m)
#pragma unroll
        for (int j = 0; j < 2; ++j)
          acc[m][j] = __builtin_amdgcn_mfma_f32_16x16x32_bf16(af[m], bfr[j], acc[m][j], 0, 0, 0);
    }
    __syncthreads();
  }
#pragma unroll
  for (int m = 0; m < 2; ++m)
#pragma unroll
    for (int j = 0; j < 2; ++j)
#pragma unroll
      for (int r = 0; r < 4; ++r)
        atomicAdd(out + (size_t)(m * 16 + l4 * 4 + r) * 1024 + (n0 + wv * 32 + j * 16 + l15),
                  acc[m][j][r]);
}

// ---------------------------------------------------------------------------
// convert_att2 v8: exactly ONE dispatch wave (256 blocks).
//   [0,128)    Wf convert
//   [128,256)  att2pre: bid2=bid-128, nt=bid2&7, ks=bid2>>3 (16 K-slots x 64,
//              single K-iteration chains). atomicAdd -> order-independent.
// ---------------------------------------------------------------------------
__global__ __launch_bounds__(256) void convert_att2(
    const float* __restrict__ wf, unsigned short* __restrict__ wfb,
    const float* __restrict__ Wd, const float* __restrict__ dh,
    float* __restrict__ att2)
{
  const int bid = blockIdx.x;
  if (bid < 128) {
    const int base = bid * 1024;
#pragma unroll
    for (int j = 0; j < 4; ++j) {
      int g = base + j * 256 + (int)threadIdx.x;
      const float* s = wf + (size_t)g * 8;
      float4 a = *reinterpret_cast<const float4*>(s);
      float4 b = *reinterpret_cast<const float4*>(s + 4);
      short8 o;
      o[0] = (short)f2b(a.x); o[1] = (short)f2b(a.y); o[2] = (short)f2b(a.z); o[3] = (short)f2b(a.w);
      o[4] = (short)f2b(b.x); o[5] = (short)f2b(b.y); o[6] = (short)f2b(b.z); o[7] = (short)f2b(b.w);
      *reinterpret_cast<short8*>(wfb + (size_t)g * 8) = o;
    }
  } else {
    int bid2 = bid - 128;
    int nt = bid2 & 7, ks = bid2 >> 3;          // ks in [0,16)
    skinny_gemm(Wd, 1024, dh, dh, dh, ks * 64, ks * 64 + 64, nt * 128, att2);
  }
}

// ---------------------------------------------------------------------------
// gate_gemm v7 (unchanged from R12): K-slots 128, dim3(8,48) = 384 blocks.
//   slot  0-23: Wg, kbeg = slot*128          -> ztp
//   slot 24-31: Ws, kbeg = (slot-24)*128     -> scp
//   slot 32-47: Wt, kbeg = (slot-32)*128     -> tcp
// ---------------------------------------------------------------------------
__global__ __launch_bounds__(256) void gate_gemm(
    const float* __restrict__ Wg, const float* __restrict__ Ws_,
    const float* __restrict__ Wt, const float* __restrict__ word,
    const float* __restrict__ dh, const float* __restrict__ ctx,
    float* __restrict__ ztp, float* __restrict__ scp, float* __restrict__ tcp)
{
  const int nt = blockIdx.x, slot = blockIdx.y;
  if (slot < 24)
    skinny_gemm(Wg, 3072, word, dh, ctx, slot * 128, slot * 128 + 128, nt * 128, ztp);
  else if (slot < 32)
    skinny_gemm(Ws_, 1024, ctx, ctx, ctx, (slot - 24) * 128, (slot - 24) * 128 + 128, nt * 128, scp);
  else
    skinny_gemm(Wt, 2048, word, dh, dh, (slot - 32) * 128, (slot - 32) * 128 + 128, nt * 128, tcp);
}

// ---------------------------------------------------------------------------
// att_gemm3 v5 (best-measured: 103.3-106 us, MfmaUtil ~27, VGPR 128):
// UNCHANGED — the band floor of this structure; 5 structural variants all
// regressed. Fused A-conversion with CROSS-BARRIER register staging.
// 128 VGPR + 128 acc = 256 unified regs = exactly 2 waves/SIMD; 128 KB LDS
// = 1 block/CU (measured cliffs both).
// ---------------------------------------------------------------------------
__global__ __launch_bounds__(512, 2) void att_gemm3(
    const float* __restrict__ cap, const unsigned short* __restrict__ wfb,
    const float* __restrict__ att2pre, const float* __restrict__ bfv,
    const float* __restrict__ bdv, const float* __restrict__ Wa,
    float* __restrict__ scores)
{
  __shared__ __align__(16) unsigned char lds[131072];   // 2 slots x (A 32K + B 32K)
  const int tid = threadIdx.x, lane = tid & 63, wv = tid >> 6;
  // bijective XCD chunking: nwg=512, 8 XCDs, 64 jobs/XCD
  const int j = ((int)blockIdx.x & 7) * 64 + ((int)blockIdx.x >> 3);
  const int mt = j >> 2, nt = j & 3;            // 128 m-tiles x 4 n-tiles
  const int m0 = mt << 8, n0 = nt << 8;
  const int bb = m0 >> 10;                      // batch (256 | 1024)
  const int wm = wv >> 2, wn = wv & 3;          // 2M x 4N
  const int l15 = lane & 15, l4 = lane >> 4;
  const int r8 = lane >> 3, c8 = lane & 7;
  const unsigned swb = (unsigned)((l15 & 7) << 4);

  // A staging source: f32, inverse-swizzled column (bf16 byte off / 2).
  const float* capA = cap + (size_t)(m0 + wv * 32 + r8) * 1024 +
                      ((unsigned)((c8 * 16) ^ (r8 << 4)) >> 1);
  // B stage source (bf16 wfb, DMA path)
  const unsigned char* bSrc = (const unsigned char*)wfb +
      (size_t)(n0 + wv * 32 + r8) * 2048 + ((c8 * 16) ^ (r8 << 4));
  const unsigned ldsBase = (unsigned)(size_t)(&lds[0]);

  f32x4 acc[8][4];
#pragma unroll
  for (int mf = 0; mf < 8; ++mf)
#pragma unroll
    for (int nf = 0; nf < 4; ++nf) acc[mf][nf] = (f32x4){0.f, 0.f, 0.f, 0.f};

#define STAGE_B(t) do { \
    const int sl__ = (t) & 1; \
    unsigned char* db__ = lds + sl__ * 65536 + 32768 + wv * 4096; \
    const unsigned char* gb__ = bSrc + (t) * 128; \
    GLOAD_LDS16(gb__,          db__); \
    GLOAD_LDS16(gb__ + 16384,  db__ + 1024); \
    GLOAD_LDS16(gb__ + 32768,  db__ + 2048); \
    GLOAD_LDS16(gb__ + 49152,  db__ + 3072); \
  } while (0)

// load one j-chunk pair (rows j0*8.. and (j0+1)*8..) of tile tt into 4 float4
#define FLIGHT(fA0, fA1, fB0, fB1, j0, tt) do { \
    const float* p0__ = capA + (size_t)(j0) * 8192 + (tt) * 64; \
    const float* p1__ = p0__ + 8192; \
    fA0 = *reinterpret_cast<const float4*>(p0__); \
    fA1 = *reinterpret_cast<const float4*>(p0__ + 4); \
    fB0 = *reinterpret_cast<const float4*>(p1__); \
    fB1 = *reinterpret_cast<const float4*>(p1__ + 4); \
  } while (0)

// convert 8 floats -> 16B bf16, store to LDS (linear lane*16: conflict-free)
#define PACK_WRITE(fA, fB, wp) do { \
    short8 o__; \
    o__[0] = (short)f2b(fA.x); o__[1] = (short)f2b(fA.y); \
    o__[2] = (short)f2b(fA.z); o__[3] = (short)f2b(fA.w); \
    o__[4] = (short)f2b(fB.x); o__[5] = (short)f2b(fB.y); \
    o__[6] = (short)f2b(fB.z); o__[7] = (short)f2b(fB.w); \
    *reinterpret_cast<short8*>(wp) = o__; \
  } while (0)

#define DSREAD(dst, addr) \
  asm volatile("ds_read_b128 %0, %1" : "=v"(dst) : "v"(addr))

// read one A quarter (32 rows): 4 x ds_read_b128 into dst[0..3]
#define READ_AQ(dst, q) do { \
_Pragma("unroll") \
    for (int mf2 = 0; mf2 < 2; ++mf2) \
_Pragma("unroll") \
      for (int ks = 0; ks < 2; ++ks) { \
        unsigned r__ = (unsigned)(wm * 128 + (q) * 32 + mf2 * 16 + l15); \
        DSREAD(dst[mf2 * 2 + ks], sA + r__ * 128 + (((unsigned)(ks * 64 + l4 * 16)) ^ swb)); \
      } \
  } while (0)

// read one B column-half (32 cols): 4 x ds_read_b128 into Breg[ch*4 ..]
#define READ_B(ch) do { \
_Pragma("unroll") \
    for (int nf = 0; nf < 2; ++nf) \
_Pragma("unroll") \
      for (int ks = 0; ks < 2; ++ks) { \
        unsigned c__ = (unsigned)(wn * 64 + (ch) * 32 + nf * 16 + l15); \
        DSREAD(Breg[(ch) * 4 + nf * 2 + ks], sB + c__ * 128 + (((unsigned)(ks * 64 + l4 * 16)) ^ swb)); \
      } \
  } while (0)

// 8 MFMAs: quarter q (rows q*32..+31) x column-half ch (cols ch*32..+31)
#define MFMA8(q, ch, Aq) do { \
    __builtin_amdgcn_s_setprio(1); \
_Pragma("unroll") \
    for (int mf2 = 0; mf2 < 2; ++mf2) \
_Pragma("unroll") \
      for (int nf = 0; nf < 2; ++nf) \
_Pragma("unroll") \
        for (int ks = 0; ks < 2; ++ks) \
          acc[(q) * 2 + mf2][(ch) * 2 + nf] = __builtin_amdgcn_mfma_f32_16x16x32_bf16( \
              Aq[mf2 * 2 + ks], Breg[(ch) * 4 + nf * 2 + ks], acc[(q) * 2 + mf2][(ch) * 2 + nf], 0, 0, 0); \
    __builtin_amdgcn_s_setprio(0); \
  } while (0)

#define WAIT_LGKM(n) do { \
    asm volatile("s_waitcnt lgkmcnt(" #n ")" ::: "memory"); \
    __builtin_amdgcn_sched_barrier(0); \
  } while (0)

  short8 Aq0[4], Aq1[4], Breg[8];
  float4 g0a, g0b, g1a, g1b;   // flight 1 (j-chunks 0,1)
  float4 g2a, g2b, g3a, g3b;   // flight 2 (j-chunks 2,3)

  // prologue: stage B(0) DMA + A(0) flights; drain; pack A(0) -> slot 0;
  // issue A(1) flights (held in regs, packed at top of t=0); join.
  STAGE_B(0);
  FLIGHT(g0a, g0b, g1a, g1b, 0, 0);
  FLIGHT(g2a, g2b, g3a, g3b, 2, 0);
  asm volatile("s_waitcnt vmcnt(0)" ::: "memory");
  {
    unsigned char* wp = lds + wv * 4096 + lane * 16;   // A slot 0
    PACK_WRITE(g0a, g0b, wp);
    PACK_WRITE(g1a, g1b, wp + 1024);
    PACK_WRITE(g2a, g2b, wp + 2048);
    PACK_WRITE(g3a, g3b, wp + 3072);
  }
  FLIGHT(g0a, g0b, g1a, g1b, 0, 1);
  FLIGHT(g2a, g2b, g3a, g3b, 2, 1);
  WAIT_LGKM(0);
  asm volatile("s_barrier" ::: "memory");

  for (int t = 0; t < 16; ++t) {
    const unsigned sA = ldsBase + (unsigned)((t & 1) * 65536);
    const unsigned sB = sA + 32768u;

    // (1) pack A(t+1) from flights issued in tile t-1 (full-tile cover)
    if (t < 15) {
      asm volatile("s_waitcnt vmcnt(0)" ::: "memory");
      __builtin_amdgcn_sched_barrier(0);
      unsigned char* wp = lds + ((t + 1) & 1) * 65536 + wv * 4096 + lane * 16;
      PACK_WRITE(g0a, g0b, wp);
      PACK_WRITE(g1a, g1b, wp + 1024);
      PACK_WRITE(g2a, g2b, wp + 2048);
      PACK_WRITE(g3a, g3b, wp + 3072);
    }
    // (2) stage B(t+1) via DMA (drained at end-of-tile wait)
    if (t < 15) STAGE_B(t + 1);

    // (3) read bursts for tile t (ds queue: [4 writes] + 16 reads)
    READ_AQ(Aq0, 0);
    READ_B(0);
    READ_B(1);
    READ_AQ(Aq1, 1);

    // (4) quarter-pipelined MFMA schedule (R2-proven)
    WAIT_LGKM(8);                       // writes + AQ0 + B(ch0) done
    MFMA8(0, 0, Aq0);
    WAIT_LGKM(4);                       // + B(ch1) done
    MFMA8(0, 1, Aq0);
    WAIT_LGKM(0);                       // + AQ1 done
    READ_AQ(Aq0, 2);                    // prefetch q2 (reuse Aq0)
    MFMA8(1, 0, Aq1);
    MFMA8(1, 1, Aq1);
    READ_AQ(Aq1, 3);                    // prefetch q3
    WAIT_LGKM(4);                       // AQ2 done (AQ3 in flight)
    MFMA8(2, 0, Aq0);
    MFMA8(2, 1, Aq0);
    // (5) flights for A(t+2): issued here, packed at top of t+1
    if (t < 14) FLIGHT(g0a, g0b, g1a, g1b, 0, t + 2);
    WAIT_LGKM(0);                       // AQ3 done
    MFMA8(3, 0, Aq1);
    MFMA8(3, 1, Aq1);
    if (t < 14) FLIGHT(g2a, g2b, g3a, g3b, 2, t + 2);

    // (6) end: drain only B-DMA (keep flights in flight), join
    if (t < 15) {
      if (t < 14) {
        asm volatile("s_waitcnt vmcnt(8)" ::: "memory");  // leave 8 flights
      } else {
        asm volatile("s_waitcnt vmcnt(0)" ::: "memory");  // only B DMA left
      }
      asm volatile("s_barrier" ::: "memory");
    }
  }

  // epilogue: s[m] = sum_n tanh(acc + colb[n]) * Wa[n], reduce over l15
  float colb[4], wav[4];
#pragma unroll
  for (int nf = 0; nf < 4; ++nf) {
    int cg = n0 + wn * 64 + nf * 16 + l15;
    colb[nf] = att2pre[bb * 1024 + cg] + bfv[cg] + bdv[cg];
    wav[nf]  = Wa[cg];
  }
#pragma unroll
  for (int mf = 0; mf < 8; ++mf) {
#pragma unroll
    for (int r = 0; r < 4; ++r) {
      float s = tanh_fast(acc[mf][0][r] + colb[0]) * wav[0]
              + tanh_fast(acc[mf][1][r] + colb[1]) * wav[1]
              + tanh_fast(acc[mf][2][r] + colb[2]) * wav[2]
              + tanh_fast(acc[mf][3][r] + colb[3]) * wav[3];
      s += __shfl_xor(s, 1);
      s += __shfl_xor(s, 2);
      s += __shfl_xor(s, 4);
      s += __shfl_xor(s, 8);
      if (l15 == 0)
        atomicAdd(scores + (m0 + wm * 128 + mf * 16 + l4 * 4 + r), s);
    }
  }
#undef STAGE_B
#undef FLIGHT
#undef PACK_WRITE
#undef DSREAD
#undef READ_AQ
#undef READ_B
#undef MFMA8
#undef WAIT_LGKM
}

// ---------------------------------------------------------------------------
// sm_ctx_k (unchanged from R12): fused softmax + context, dim3(16,32).
// ---------------------------------------------------------------------------
__global__ __launch_bounds__(256) void sm_ctx_k(
    const float* __restrict__ scores, const int* __restrict__ mask,
    const float* __restrict__ cap, float* __restrict__ alpha,
    float* __restrict__ ctx)
{
  const int b = blockIdx.y, lc = blockIdx.x, tid = threadIdx.x;
  __shared__ float red[8];
  __shared__ float aChunk[64];
  float s[4];
  float mx = -3.0e38f;
#pragma unroll
  for (int i = 0; i < 4; ++i) {
    int l = tid + i * 256;
    float v = scores[b * 1024 + l];
    v = (mask[b * 1024 + l] == 0) ? -1.0e10f : v;
    s[i] = v;
    mx = fmaxf(mx, v);
  }
  for (int off = 1; off < 64; off <<= 1) mx = fmaxf(mx, __shfl_xor(mx, off));
  int wv = tid >> 6;
  if ((tid & 63) == 0) red[wv] = mx;
  __syncthreads();
  mx = fmaxf(fmaxf(red[0], red[1]), fmaxf(red[2], red[3]));
  float sum = 0.f;
#pragma unroll
  for (int i = 0; i < 4; ++i) {
    s[i] = exp2f_fast((s[i] - mx) * LOG2E);
    sum += s[i];
  }
  for (int off = 1; off < 64; off <<= 1) sum += __shfl_xor(sum, off);
  if ((tid & 63) == 0) red[4 + wv] = sum;
  __syncthreads();
  sum = red[4] + red[5] + red[6] + red[7];
  float inv = 1.0f / sum;

  // write this block's alpha chunk [lc*64, lc*64+64)
  const int i0 = lc >> 2, t0 = (lc & 3) * 64;
  if ((unsigned)(tid - t0) < 64u) {
    float av = s[i0] * inv;
    alpha[b * 1024 + lc * 64 + (tid - t0)] = av;
    aChunk[tid - t0] = av;
  }
  __syncthreads();

  // ctx accumulation over this 64-l chunk
  const int dc = tid & 127, loff = tid >> 7;
  float acc[8] = {0.f, 0.f, 0.f, 0.f, 0.f, 0.f, 0.f, 0.f};
  for (int li = loff; li < 64; li += 2) {
    float av = aChunk[li];
    if (av != 0.f) {                     // wave-uniform (li uniform)
      const float* p = cap + (((size_t)(b * 1024 + lc * 64 + li)) << 10) + dc * 8;
      float4 v0 = *reinterpret_cast<const float4*>(p);
      float4 v1 = *reinterpret_cast<const float4*>(p + 4);
      acc[0] += av * v0.x; acc[1] += av * v0.y;
      acc[2] += av * v0.z; acc[3] += av * v0.w;
      acc[4] += av * v1.x; acc[5] += av * v1.y;
      acc[6] += av * v1.z; acc[7] += av * v1.w;
    }
  }
#pragma unroll
  for (int j = 0; j < 8; ++j) atomicAdd(ctx + b * 1024 + dc * 8 + j, acc[j]);
}

// ---------------------------------------------------------------------------
__global__ __launch_bounds__(256) void final_k(
    const float* __restrict__ ztp, const float* __restrict__ scp,
    const float* __restrict__ tcp, const float* __restrict__ bg,
    const float* __restrict__ bs, const float* __restrict__ bt,
    float* __restrict__ out)
{
  const int idx = blockIdx.x * 256 + threadIdx.x;
  const int d = idx & 1023;
  float z  = rcp_fast(1.0f + exp2f_fast(-(ztp[idx] + bg[d]) * LOG2E));
  float sc = tanh_fast(scp[idx] + bs[d]);
  float tc = tanh_fast(tcp[idx] + bt[d]);
  out[idx] = z * sc + (1.0f - z) * tc;
}

extern "C" void kernel_launch(void* const* d_in, const int* in_sizes, int n_in,
                              void* d_out, int out_size, void* d_ws, size_t ws_size,
                              hipStream_t stream) {
  const float* cap  = (const float*)d_in[0];
  const float* dh   = (const float*)d_in[1];
  const float* word = (const float*)d_in[2];
  const int*   mask = (const int*)d_in[3];
  const float* Wf   = (const float*)d_in[4];
  const float* bf   = (const float*)d_in[5];
  const float* Wd   = (const float*)d_in[6];
  const float* bd   = (const float*)d_in[7];
  const float* Wa   = (const float*)d_in[8];
  // d_in[9] = ba: softmax-invariant, dropped.
  const float* Wg   = (const float*)d_in[10];
  const float* bg   = (const float*)d_in[11];
  const float* Ws   = (const float*)d_in[12];
  const float* bs   = (const float*)d_in[13];
  const float* Wt   = (const float*)d_in[14];
  const float* bt   = (const float*)d_in[15];

  float* out_g = (float*)d_out;            // (32,1024) gated_context
  float* alpha = (float*)d_out + 32768;    // (32,1024) alpha

  float* att2pre = (float*)d_ws;           // 6 x 32768 f32 (zeroed)
  float* scores  = att2pre + 32768;
  float* ctx     = scores + 32768;
  float* ztp     = ctx + 32768;
  float* scp     = ztp + 32768;
  float* tcp     = scp + 32768;
  unsigned short* wfb = (unsigned short*)((char*)d_ws + 786432);  // 2 MB

  hipMemsetAsync(d_ws, 0, 6 * 32768 * sizeof(float), stream);

  convert_att2<<<256, 256, 0, stream>>>(Wf, wfb, Wd, dh, att2pre);
  att_gemm3<<<512, 512, 0, stream>>>(cap, wfb, att2pre, bf, bd, Wa, scores);
  sm_ctx_k<<<dim3(16, 32), 256, 0, stream>>>(scores, mask, cap, alpha, ctx);
  gate_gemm<<<dim3(8, 48), 256, 0, stream>>>(Wg, Ws, Wt, word, dh, ctx, ztp, scp, tcp);
  final_k<<<128, 256, 0, stream>>>(ztp, scp, tcp, bg, bs, bt, out_g);
}